// Round 2
// baseline (1982.273 us; speedup 1.0000x reference)
//
#include <hip/hip_runtime.h>
#include <hip/hip_bf16.h>
#include <math.h>

typedef __hip_bfloat16 bf16;

#define BATCH 2
#define SEQ 1024
#define DM 1024
#define DI 2048
#define NST 16
#define DTR 64
#define XDN 96          // dt_rank + 2*N = 64+32
#define T_TOK 2048      // BATCH*SEQ
#define N2 4096         // 2*DI

static __device__ __forceinline__ float bits2f(unsigned short u) {
    return __uint_as_float(((unsigned)u) << 16);
}
static __device__ __forceinline__ float b2f(bf16 v) { return __bfloat162float(v); }

// ---------------- LayerNorm: x(f32, T x DM) -> H(bf16) ----------------
__global__ __launch_bounds__(256) void ln_kernel(const float* __restrict__ x,
                                                 const float* __restrict__ gamma,
                                                 const float* __restrict__ beta,
                                                 bf16* __restrict__ H) {
    int t = blockIdx.x;
    int tid = threadIdx.x;
    float xv[4];
    float s = 0.f, s2 = 0.f;
#pragma unroll
    for (int k = 0; k < 4; ++k) {
        float v = x[(size_t)t * DM + k * 256 + tid];
        xv[k] = v; s += v; s2 += v * v;
    }
#pragma unroll
    for (int off = 32; off; off >>= 1) {
        s  += __shfl_down(s, off);
        s2 += __shfl_down(s2, off);
    }
    __shared__ float red[8];
    int wid = tid >> 6, lane = tid & 63;
    if (!lane) { red[wid] = s; red[4 + wid] = s2; }
    __syncthreads();
    if (tid == 0) {
        float S = red[0] + red[1] + red[2] + red[3];
        float S2 = red[4] + red[5] + red[6] + red[7];
        float mu = S * (1.f / DM);
        float var = S2 * (1.f / DM) - mu * mu;
        red[0] = mu;
        red[1] = rsqrtf(var + 1e-5f);
    }
    __syncthreads();
    float mu = red[0], rs = red[1];
#pragma unroll
    for (int k = 0; k < 4; ++k) {
        int i = k * 256 + tid;
        H[(size_t)t * DM + i] = __float2bfloat16((xv[k] - mu) * rs * gamma[i] + beta[i]);
    }
}

// ---------------- A-tile loaders (4 contiguous elements -> f32) ----------------
static __device__ __forceinline__ void loadA4(const float* p, float v[4]) {
    float4 t = *reinterpret_cast<const float4*>(p);
    v[0] = t.x; v[1] = t.y; v[2] = t.z; v[3] = t.w;
}
static __device__ __forceinline__ void loadA4(const bf16* p, float v[4]) {
    ushort4 t = *reinterpret_cast<const ushort4*>(p);
    v[0] = bits2f(t.x); v[1] = bits2f(t.y); v[2] = bits2f(t.z); v[3] = bits2f(t.w);
}

// ---------------- Generic tiled GEMM: A(MxK, TA, lda) * B(KxN, f32) ----------------
// EPI 0: store bf16 to Cb
// EPI 1: outf = resid_f32 + acc   (f32 store, final output)
// EPI 2: Cb = bf16( softplus(acc + bias_f32[n]) )
template <typename TA, int EPI>
__global__ __launch_bounds__(256) void gemm_kernel(const TA* __restrict__ A, int lda,
                                                   const float* __restrict__ Bw,
                                                   bf16* __restrict__ Cb,
                                                   const float* __restrict__ bias,
                                                   const float* __restrict__ resid,
                                                   float* __restrict__ outf,
                                                   int M, int N, int K) {
    __shared__ float As[16][68];
    __shared__ float Bs[16][68];
    int tid = threadIdx.x;
    int bm = blockIdx.y * 64, bn = blockIdx.x * 64;
    int tx = tid & 15, ty = tid >> 4;
    float acc[4][4];
#pragma unroll
    for (int i = 0; i < 4; ++i)
#pragma unroll
        for (int j = 0; j < 4; ++j) acc[i][j] = 0.f;

    int arow = tid >> 2;          // 0..63
    int acg  = (tid & 3) * 4;     // 0,4,8,12
    int brow = tid >> 4;          // 0..15
    int bcol = (tid & 15) * 4;    // 0..60

    for (int k0 = 0; k0 < K; k0 += 16) {
        float av[4];
        loadA4(&A[(size_t)(bm + arow) * lda + k0 + acg], av);
        As[acg + 0][arow] = av[0];
        As[acg + 1][arow] = av[1];
        As[acg + 2][arow] = av[2];
        As[acg + 3][arow] = av[3];
        float4 bv = *reinterpret_cast<const float4*>(&Bw[(size_t)(k0 + brow) * N + bn + bcol]);
        Bs[brow][bcol + 0] = bv.x;
        Bs[brow][bcol + 1] = bv.y;
        Bs[brow][bcol + 2] = bv.z;
        Bs[brow][bcol + 3] = bv.w;
        __syncthreads();
#pragma unroll
        for (int kk = 0; kk < 16; ++kk) {
            float4 a = *reinterpret_cast<const float4*>(&As[kk][ty * 4]);
            float4 b = *reinterpret_cast<const float4*>(&Bs[kk][tx * 4]);
            acc[0][0] += a.x * b.x; acc[0][1] += a.x * b.y; acc[0][2] += a.x * b.z; acc[0][3] += a.x * b.w;
            acc[1][0] += a.y * b.x; acc[1][1] += a.y * b.y; acc[1][2] += a.y * b.z; acc[1][3] += a.y * b.w;
            acc[2][0] += a.z * b.x; acc[2][1] += a.z * b.y; acc[2][2] += a.z * b.z; acc[2][3] += a.z * b.w;
            acc[3][0] += a.w * b.x; acc[3][1] += a.w * b.y; acc[3][2] += a.w * b.z; acc[3][3] += a.w * b.w;
        }
        __syncthreads();
    }

    int row0 = bm + ty * 4, col0 = bn + tx * 4;
#pragma unroll
    for (int i = 0; i < 4; ++i) {
#pragma unroll
        for (int j = 0; j < 4; ++j) {
            size_t idx = (size_t)(row0 + i) * N + col0 + j;
            if (EPI == 0) {
                Cb[idx] = __float2bfloat16(acc[i][j]);
            } else if (EPI == 1) {
                outf[idx] = resid[idx] + acc[i][j];
            } else {
                float v = acc[i][j] + bias[col0 + j];
                float sp = (v > 20.f) ? v : log1pf(__expf(v));
                Cb[idx] = __float2bfloat16(sp);
            }
        }
    }
}

// ---------------- depthwise causal conv (fwd) + anti-causal (bwd) + SiLU ----------------
__global__ __launch_bounds__(256) void conv_kernel(const bf16* __restrict__ XZ,
                                                   const float* __restrict__ wf, const float* __restrict__ bf_,
                                                   const float* __restrict__ wb, const float* __restrict__ bb_,
                                                   bf16* __restrict__ XCF, bf16* __restrict__ XCB) {
    int idx = blockIdx.x * 256 + threadIdx.x;   // over T_TOK*DI
    int c = idx & (DI - 1);
    int g = idx >> 11;
    int l = g & (SEQ - 1);
    int b = g >> 10;
    float sf = bf_[c];
    float sb = bb_[c];
#pragma unroll
    for (int j = 0; j < 4; ++j) {
        int lf = l - 3 + j;
        if (lf >= 0) sf += wf[c * 4 + j] * b2f(XZ[((size_t)(b * SEQ + lf)) * N2 + c]);
        int lb = l + 3 - j;
        if (lb < SEQ) sb += wb[c * 4 + j] * b2f(XZ[((size_t)(b * SEQ + lb)) * N2 + c]);
    }
    XCF[idx] = __float2bfloat16(sf / (1.f + __expf(-sf)));
    XCB[idx] = __float2bfloat16(sb / (1.f + __expf(-sb)));
}

// ---------------- transpose xproj (2048x96 f32) -> (96x2048 f32), both dirs ----------------
__global__ __launch_bounds__(256) void xproj_transpose(const float* __restrict__ xf,
                                                       const float* __restrict__ xb,
                                                       float* __restrict__ XPTF,
                                                       float* __restrict__ XPTB) {
    int idx = blockIdx.x * 256 + threadIdx.x;   // over 2*96*2048
    int dir = idx >= XDN * DI;
    int i = idx - dir * (XDN * DI);
    int n = i >> 11;
    int k = i & (DI - 1);
    (dir ? XPTB : XPTF)[i] = (dir ? xb : xf)[k * XDN + n];
}

// ---------------- x_dbl = xc @ xproj_w : wave-per-output dot ----------------
__global__ __launch_bounds__(256) void xdbl_kernel(const bf16* __restrict__ XCF, const bf16* __restrict__ XCB,
                                                   const float* __restrict__ XPTF, const float* __restrict__ XPTB,
                                                   float* __restrict__ XDF, float* __restrict__ XDB) {
    int wid = threadIdx.x >> 6, lane = threadIdx.x & 63;
    int o = blockIdx.x * 4 + wid;        // 0 .. T_TOK*96-1
    int dir = blockIdx.y;
    int t = o / XDN;
    int n = o - t * XDN;
    const bf16* xc = dir ? XCB : XCF;
    const float* xpt = dir ? XPTB : XPTF;
    float s = 0.f;
    for (int k = lane; k < DI; k += 64)
        s += b2f(xc[(size_t)t * DI + k]) * xpt[(size_t)n * DI + k];
#pragma unroll
    for (int off = 32; off; off >>= 1) s += __shfl_down(s, off);
    if (!lane) (dir ? XDB : XDF)[(size_t)t * XDN + n] = s;
}

// ---------------- selective scan (both dirs), 4-way state split per channel ----------------
__global__ __launch_bounds__(256) void scan_kernel(const bf16* __restrict__ DTF, const bf16* __restrict__ DTB,
                                                   const bf16* __restrict__ XCF, const bf16* __restrict__ XCB,
                                                   const float* __restrict__ XDF, const float* __restrict__ XDB,
                                                   const float* __restrict__ Af, const float* __restrict__ Ab,
                                                   const float* __restrict__ Df, const float* __restrict__ Db,
                                                   bf16* __restrict__ YCAT) {
    int dir = blockIdx.z;
    int b = blockIdx.y;
    int tid = threadIdx.x;
    int cl = tid & 63;
    int sub = tid >> 6;                    // 0..3 -> states sub*4..sub*4+3
    int c = blockIdx.x * 64 + cl;
    const bf16* DT = dir ? DTB : DTF;
    const bf16* XC = dir ? XCB : XCF;
    const float* XD = dir ? XDB : XDF;
    const float* Al = dir ? Ab : Af;
    const float* Dsk = dir ? Db : Df;

    float A[4];
#pragma unroll
    for (int j = 0; j < 4; ++j) A[j] = -__expf(Al[c * NST + sub * 4 + j]);
    float Dv = Dsk[c];
    float h[4] = {0.f, 0.f, 0.f, 0.f};
    __shared__ float yp[4][64];

    for (int it = 0; it < SEQ; ++it) {
        int l = dir ? (SEQ - 1 - it) : it;
        size_t g = (size_t)b * SEQ + l;
        float dt = b2f(DT[g * DI + c]);
        float xc = b2f(XC[g * DI + c]);
        float dtxc = dt * xc;
        const float* bc = &XD[g * XDN + DTR + sub * 4];
        float y = 0.f;
#pragma unroll
        for (int j = 0; j < 4; ++j) {
            float dA = __expf(dt * A[j]);
            h[j] = dA * h[j] + dtxc * bc[j];
            y += h[j] * bc[NST + j];
        }
        yp[sub][cl] = y;
        __syncthreads();
        if (sub == 0) {
            float ys = yp[0][cl] + yp[1][cl] + yp[2][cl] + yp[3][cl];
            YCAT[g * N2 + dir * DI + c] = __float2bfloat16(ys + xc * Dv);
        }
        __syncthreads();
    }
}

// ---------------- gating: YM *= silu(z) ----------------
__global__ __launch_bounds__(256) void gate_kernel(bf16* __restrict__ YM, const bf16* __restrict__ XZ) {
    int idx = blockIdx.x * 256 + threadIdx.x;  // over T_TOK*DI
    int t = idx >> 11;
    int c = idx & (DI - 1);
    float z = b2f(XZ[(size_t)t * N2 + DI + c]);
    float y = b2f(YM[idx]);
    YM[idx] = __float2bfloat16(y * (z / (1.f + __expf(-z))));
}

extern "C" void kernel_launch(void* const* d_in, const int* in_sizes, int n_in,
                              void* d_out, int out_size, void* d_ws, size_t ws_size,
                              hipStream_t stream) {
    const float* x       = (const float*)d_in[0];
    const float* gamma   = (const float*)d_in[1];
    const float* beta    = (const float*)d_in[2];
    const float* in_w    = (const float*)d_in[3];
    const float* conv_w  = (const float*)d_in[4];
    const float* conv_b  = (const float*)d_in[5];
    const float* xproj_w = (const float*)d_in[6];
    const float* dt_w    = (const float*)d_in[7];
    const float* dt_b    = (const float*)d_in[8];
    const float* A_log   = (const float*)d_in[9];
    const float* D_skip  = (const float*)d_in[10];
    const float* conv_w_b  = (const float*)d_in[11];
    const float* conv_b_b  = (const float*)d_in[12];
    const float* xproj_w_b = (const float*)d_in[13];
    const float* dt_w_b    = (const float*)d_in[14];
    const float* dt_b_b    = (const float*)d_in[15];
    const float* A_log_b   = (const float*)d_in[16];
    const float* D_skip_b  = (const float*)d_in[17];
    const float* merge_w   = (const float*)d_in[18];
    const float* out_w     = (const float*)d_in[19];
    float* out = (float*)d_out;

    // ---- workspace layout (bytes) ----
    char* w = (char*)d_ws;
    size_t off = 0;
    bf16* H    = (bf16*)(w + off); off += (size_t)T_TOK * DM * 2;    //  4.19 MB
    bf16* XZ   = (bf16*)(w + off); off += (size_t)T_TOK * N2 * 2;    // 16.78 MB
    bf16* XCF  = (bf16*)(w + off); off += (size_t)T_TOK * DI * 2;    //  8.39 MB
    bf16* XCB  = (bf16*)(w + off); off += (size_t)T_TOK * DI * 2;    //  8.39 MB
    float* XPTF = (float*)(w + off); off += (size_t)XDN * DI * 4;    //  0.79 MB
    float* XPTB = (float*)(w + off); off += (size_t)XDN * DI * 4;    //  0.79 MB
    float* XDF  = (float*)(w + off); off += (size_t)T_TOK * XDN * 4; //  0.79 MB
    float* XDB  = (float*)(w + off); off += (size_t)T_TOK * XDN * 4; //  0.79 MB
    bf16* DTF  = (bf16*)(w + off); off += (size_t)T_TOK * DI * 2;    //  8.39 MB
    bf16* DTB  = (bf16*)(w + off); off += (size_t)T_TOK * DI * 2;    //  8.39 MB
    bf16* YCAT = (bf16*)(w + off); off += (size_t)T_TOK * N2 * 2;    // 16.78 MB
    bf16* YM   = DTF;  // alias: DTF dead after scan, same size       total ~74 MB

    // 1. LayerNorm
    ln_kernel<<<T_TOK, 256, 0, stream>>>(x, gamma, beta, H);
    // 2. xz = H @ in_w  (2048 x 4096 x 1024) -> XZ bf16
    gemm_kernel<bf16, 0><<<dim3(N2 / 64, T_TOK / 64), 256, 0, stream>>>(
        H, DM, in_w, XZ, nullptr, nullptr, nullptr, T_TOK, N2, DM);
    // 3. depthwise conv + silu, both dirs
    conv_kernel<<<(T_TOK * DI) / 256, 256, 0, stream>>>(XZ, conv_w, conv_b, conv_w_b, conv_b_b, XCF, XCB);
    // 4. transpose xproj weights
    xproj_transpose<<<(2 * XDN * DI) / 256, 256, 0, stream>>>(xproj_w, xproj_w_b, XPTF, XPTB);
    // 5. x_dbl = xc @ xproj (wave-dot)
    xdbl_kernel<<<dim3((T_TOK * XDN) / 4, 2), 256, 0, stream>>>(XCF, XCB, XPTF, XPTB, XDF, XDB);
    // 6. dt = softplus(x_dbl[:, :64] @ dt_w + dt_b) -> bf16
    gemm_kernel<float, 2><<<dim3(DI / 64, T_TOK / 64), 256, 0, stream>>>(
        XDF, XDN, dt_w, DTF, dt_b, nullptr, nullptr, T_TOK, DI, DTR);
    gemm_kernel<float, 2><<<dim3(DI / 64, T_TOK / 64), 256, 0, stream>>>(
        XDB, XDN, dt_w_b, DTB, dt_b_b, nullptr, nullptr, T_TOK, DI, DTR);
    // 7. selective scan both dirs -> YCAT (T x 4096) bf16
    scan_kernel<<<dim3(DI / 64, BATCH, 2), 256, 0, stream>>>(
        DTF, DTB, XCF, XCB, XDF, XDB, A_log, A_log_b, D_skip, D_skip_b, YCAT);
    // 8. YM = YCAT @ merge_w (2048 x 2048 x 4096) -> bf16 (aliases DTF)
    gemm_kernel<bf16, 0><<<dim3(DI / 64, T_TOK / 64), 256, 0, stream>>>(
        YCAT, N2, merge_w, YM, nullptr, nullptr, nullptr, T_TOK, DI, N2);
    // 9. YM *= silu(z)
    gate_kernel<<<(T_TOK * DI) / 256, 256, 0, stream>>>(YM, XZ);
    // 10. out = x + YM @ out_w (2048 x 1024 x 2048), f32 store
    gemm_kernel<bf16, 1><<<dim3(DM / 64, T_TOK / 64), 256, 0, stream>>>(
        YM, DI, out_w, nullptr, nullptr, x, out, T_TOK, DM, DI);
}

// Round 3
// 600.878 us; speedup vs baseline: 3.2990x; 3.2990x over previous
//
#include <hip/hip_runtime.h>
#include <hip/hip_bf16.h>
#include <math.h>

typedef __hip_bfloat16 bf16;
typedef unsigned int u32;
typedef __attribute__((ext_vector_type(8))) short bf16x8;
typedef __attribute__((ext_vector_type(4))) float f32x4;

#define BATCH 2
#define SEQ 1024
#define DM 1024
#define DI 2048
#define NST 16
#define DTR 64
#define XDN 96          // dt_rank + 2*N = 64+32
#define XDP_LD 128      // padded x_dbl row
#define T_TOK 2048      // BATCH*SEQ
#define N2 4096         // 2*DI
#define NCHUNK 16
#define CLEN 64

static __device__ __forceinline__ float b2f(bf16 v) { return __bfloat162float(v); }

// ---- async global->LDS, 16 bytes per lane; LDS dest must be wave-uniform base ----
static __device__ __forceinline__ void gload_lds16(const void* g, void* l) {
    __builtin_amdgcn_global_load_lds((__attribute__((address_space(1))) u32*)(size_t)g,
                                     (__attribute__((address_space(3))) u32*)l, 16, 0, 0);
}

// ---------------- LayerNorm: x(f32, T x DM) -> H(bf16) ----------------
__global__ __launch_bounds__(256) void ln_kernel(const float* __restrict__ x,
                                                 const float* __restrict__ gamma,
                                                 const float* __restrict__ beta,
                                                 bf16* __restrict__ H) {
    int t = blockIdx.x;
    int tid = threadIdx.x;
    float xv[4];
    float s = 0.f, s2 = 0.f;
#pragma unroll
    for (int k = 0; k < 4; ++k) {
        float v = x[(size_t)t * DM + k * 256 + tid];
        xv[k] = v; s += v; s2 += v * v;
    }
#pragma unroll
    for (int off = 32; off; off >>= 1) {
        s  += __shfl_down(s, off);
        s2 += __shfl_down(s2, off);
    }
    __shared__ float red[8];
    int wid = tid >> 6, lane = tid & 63;
    if (!lane) { red[wid] = s; red[4 + wid] = s2; }
    __syncthreads();
    if (tid == 0) {
        float S = red[0] + red[1] + red[2] + red[3];
        float S2 = red[4] + red[5] + red[6] + red[7];
        float mu = S * (1.f / DM);
        float var = S2 * (1.f / DM) - mu * mu;
        red[0] = mu;
        red[1] = rsqrtf(var + 1e-5f);
    }
    __syncthreads();
    float mu = red[0], rs = red[1];
#pragma unroll
    for (int k = 0; k < 4; ++k) {
        int i = k * 256 + tid;
        H[(size_t)t * DM + i] = __float2bfloat16((xv[k] - mu) * rs * gamma[i] + beta[i]);
    }
}

// ---------------- weight prep: fp32 [K][N] -> bf16 [N][K] (transpose + convert) ----------------
__global__ __launch_bounds__(256) void transpose_cvt(const float* __restrict__ in,
                                                     bf16* __restrict__ out, int K, int N) {
    __shared__ float t[32][33];
    int bx = blockIdx.x * 32;  // N base
    int by = blockIdx.y * 32;  // K base
    int tx = threadIdx.x;
    for (int r = threadIdx.y; r < 32; r += 8)
        t[r][tx] = in[(size_t)(by + r) * N + bx + tx];
    __syncthreads();
    for (int r = threadIdx.y; r < 32; r += 8)
        out[(size_t)(bx + r) * K + by + tx] = __float2bfloat16(t[tx][r]);
}

// ---------------- xproj prep: fp32 [2048][96] -> bf16 [128][2048], rows >=96 zero ----------------
__global__ __launch_bounds__(256) void xproj_prep(const float* __restrict__ xf,
                                                  const float* __restrict__ xb,
                                                  bf16* __restrict__ XPF, bf16* __restrict__ XPB) {
    int idx = blockIdx.x * 256 + threadIdx.x;   // over 2*128*2048
    int dir = idx >= XDP_LD * DI;
    int i = idx - dir * (XDP_LD * DI);
    int n = i >> 11;
    int k = i & (DI - 1);
    float v = (n < XDN) ? (dir ? xb : xf)[k * XDN + n] : 0.f;
    (dir ? XPB : XPF)[i] = __float2bfloat16(v);
}

// ---------------- MFMA GEMM: C(MxN) = A(MxK,bf16,row-major) * BT(NxK,bf16)^T ----------------
// 128x128 tile, BK=64, 4 waves each 64x64 (4x4 of 16x16x32 MFMA)
// EPI 0: bf16 store to Cb;  EPI 1: outf = resid + acc (f32);  EPI 2: f32 store to outf
template <int EPI>
__global__ __launch_bounds__(256) void mfma_gemm(const bf16* __restrict__ A,
                                                 const bf16* __restrict__ BT,
                                                 const bf16* __restrict__ BT2, int bysplit,
                                                 bf16* __restrict__ Cb,
                                                 const float* __restrict__ resid,
                                                 float* __restrict__ outf,
                                                 int M, int N, int K) {
    __shared__ bf16 As[8192];   // [kg 0..7][m 0..127][8]
    __shared__ bf16 Bs[8192];   // [kg 0..7][n 0..127][8]
    int tid = threadIdx.x;
    int wave = tid >> 6, lane = tid & 63;
    int q = lane >> 4, ln16 = lane & 15;
    int bm = blockIdx.y * 128, bn = blockIdx.x * 128;
    int wm = (wave >> 1) * 64, wn = (wave & 1) * 64;
    const bf16* Bt = ((int)blockIdx.y < bysplit) ? BT : BT2;

    f32x4 zf; zf[0] = zf[1] = zf[2] = zf[3] = 0.f;
    f32x4 acc[4][4];
#pragma unroll
    for (int i = 0; i < 4; ++i)
#pragma unroll
        for (int j = 0; j < 4; ++j) acc[i][j] = zf;

    for (int k0 = 0; k0 < K; k0 += 64) {
#pragma unroll
        for (int i = 0; i < 4; ++i) {
            int s = wave * 256 + i * 64 + lane;   // slot 0..1023
            int kg = s >> 7, m = s & 127;
            gload_lds16(&A[(size_t)(bm + m) * K + k0 + kg * 8], &As[(wave * 256 + i * 64) * 8]);
            gload_lds16(&Bt[(size_t)(bn + m) * K + k0 + kg * 8], &Bs[(wave * 256 + i * 64) * 8]);
        }
        __syncthreads();
#pragma unroll
        for (int kk = 0; kk < 2; ++kk) {
            bf16x8 af[4], bfr[4];
#pragma unroll
            for (int i = 0; i < 4; ++i) {
                af[i]  = *(const bf16x8*)&As[(((kk * 4 + q) * 128) + (wm + i * 16 + ln16)) * 8];
                bfr[i] = *(const bf16x8*)&Bs[(((kk * 4 + q) * 128) + (wn + i * 16 + ln16)) * 8];
            }
#pragma unroll
            for (int i = 0; i < 4; ++i)
#pragma unroll
                for (int j = 0; j < 4; ++j)
                    acc[i][j] = __builtin_amdgcn_mfma_f32_16x16x32_bf16(af[i], bfr[j], acc[i][j], 0, 0, 0);
        }
        __syncthreads();
    }

#pragma unroll
    for (int i = 0; i < 4; ++i)
#pragma unroll
        for (int r = 0; r < 4; ++r) {
            int row = bm + wm + i * 16 + q * 4 + r;
#pragma unroll
            for (int j = 0; j < 4; ++j) {
                int col = bn + wn + j * 16 + ln16;
                size_t idx = (size_t)row * N + col;
                float v = acc[i][j][r];
                if (EPI == 0)      Cb[idx] = __float2bfloat16(v);
                else if (EPI == 1) outf[idx] = resid[idx] + v;
                else               outf[idx] = v;
            }
        }
}

// ---------------- dt GEMM (vector, K=64): DT = softplus(XDP[:, :64] @ dt_w + dt_b) -> bf16 ----------------
__global__ __launch_bounds__(256) void gemm_dt(const float* __restrict__ A,   // lda=128
                                               const float* __restrict__ Bw,  // 64 x 2048 f32
                                               const float* __restrict__ bias,
                                               bf16* __restrict__ Cb, int M, int N) {
    __shared__ float As[16][68];
    __shared__ float Bs[16][68];
    int tid = threadIdx.x;
    int bm = blockIdx.y * 64, bn = blockIdx.x * 64;
    int tx = tid & 15, ty = tid >> 4;
    float acc[4][4];
#pragma unroll
    for (int i = 0; i < 4; ++i)
#pragma unroll
        for (int j = 0; j < 4; ++j) acc[i][j] = 0.f;
    int arow = tid >> 2, acg = (tid & 3) * 4;
    int brow = tid >> 4, bcol = (tid & 15) * 4;
    for (int k0 = 0; k0 < DTR; k0 += 16) {
        float4 av = *reinterpret_cast<const float4*>(&A[(size_t)(bm + arow) * XDP_LD + k0 + acg]);
        As[acg + 0][arow] = av.x; As[acg + 1][arow] = av.y;
        As[acg + 2][arow] = av.z; As[acg + 3][arow] = av.w;
        float4 bv = *reinterpret_cast<const float4*>(&Bw[(size_t)(k0 + brow) * N + bn + bcol]);
        Bs[brow][bcol + 0] = bv.x; Bs[brow][bcol + 1] = bv.y;
        Bs[brow][bcol + 2] = bv.z; Bs[brow][bcol + 3] = bv.w;
        __syncthreads();
#pragma unroll
        for (int kk = 0; kk < 16; ++kk) {
            float4 a = *reinterpret_cast<const float4*>(&As[kk][ty * 4]);
            float4 b = *reinterpret_cast<const float4*>(&Bs[kk][tx * 4]);
            acc[0][0] += a.x * b.x; acc[0][1] += a.x * b.y; acc[0][2] += a.x * b.z; acc[0][3] += a.x * b.w;
            acc[1][0] += a.y * b.x; acc[1][1] += a.y * b.y; acc[1][2] += a.y * b.z; acc[1][3] += a.y * b.w;
            acc[2][0] += a.z * b.x; acc[2][1] += a.z * b.y; acc[2][2] += a.z * b.z; acc[2][3] += a.z * b.w;
            acc[3][0] += a.w * b.x; acc[3][1] += a.w * b.y; acc[3][2] += a.w * b.z; acc[3][3] += a.w * b.w;
        }
        __syncthreads();
    }
    int row0 = bm + ty * 4, col0 = bn + tx * 4;
#pragma unroll
    for (int i = 0; i < 4; ++i)
#pragma unroll
        for (int j = 0; j < 4; ++j) {
            float v = acc[i][j] + bias[col0 + j];
            float sp = (v > 20.f) ? v : log1pf(__expf(v));
            Cb[(size_t)(row0 + i) * N + col0 + j] = __float2bfloat16(sp);
        }
}

// ---------------- depthwise causal conv (fwd) + anti-causal (bwd) + SiLU ----------------
__global__ __launch_bounds__(256) void conv_kernel(const bf16* __restrict__ XZ,
                                                   const float* __restrict__ wf, const float* __restrict__ bf_,
                                                   const float* __restrict__ wb, const float* __restrict__ bb_,
                                                   bf16* __restrict__ XCF, bf16* __restrict__ XCB) {
    int idx = blockIdx.x * 256 + threadIdx.x;   // over T_TOK*DI
    int c = idx & (DI - 1);
    int g = idx >> 11;
    int l = g & (SEQ - 1);
    int b = g >> 10;
    float sf = bf_[c];
    float sb = bb_[c];
#pragma unroll
    for (int j = 0; j < 4; ++j) {
        int lf = l - 3 + j;
        if (lf >= 0) sf += wf[c * 4 + j] * b2f(XZ[((size_t)(b * SEQ + lf)) * N2 + c]);
        int lb = l + 3 - j;
        if (lb < SEQ) sb += wb[c * 4 + j] * b2f(XZ[((size_t)(b * SEQ + lb)) * N2 + c]);
    }
    XCF[idx] = __float2bfloat16(sf / (1.f + __expf(-sf)));
    XCB[idx] = __float2bfloat16(sb / (1.f + __expf(-sb)));
}

// ---------------- chunked selective scan ----------------
// phase A (FINAL=0): local scan from h=0, store chunk-final h (HLOC) + sum(dt) (SUMDT)
// phase C (FINAL=1): scan from exact h_in (HLOC, rewritten by phase B), emit y
template <bool FINAL>
__global__ __launch_bounds__(256) void scan_chunk(const bf16* __restrict__ DTF_, const bf16* __restrict__ DTB_,
                                                  const bf16* __restrict__ XCF_, const bf16* __restrict__ XCB_,
                                                  const float* __restrict__ XDP,
                                                  const float* __restrict__ Af, const float* __restrict__ Ab,
                                                  const float* __restrict__ Df, const float* __restrict__ Db,
                                                  float* __restrict__ HLOC, float* __restrict__ SUMDT,
                                                  bf16* __restrict__ YCAT) {
    int c = blockIdx.x * 256 + threadIdx.x;
    int b = blockIdx.y;
    int dir = blockIdx.z >> 4, chunk = blockIdx.z & 15;
    const bf16* DT = dir ? DTB_ : DTF_;
    const bf16* XC = dir ? XCB_ : XCF_;
    const float* Al = dir ? Ab : Af;
    float A[NST];
#pragma unroll
    for (int n = 0; n < NST; ++n) A[n] = -__expf(Al[c * NST + n]);
    size_t base = ((((size_t)dir * BATCH + b) * NCHUNK + chunk) * DI + c);
    float h[NST];
    float Dv = 0.f;
    if (FINAL) {
#pragma unroll
        for (int n = 0; n < NST; ++n) h[n] = HLOC[base * NST + n];
        Dv = (dir ? Db : Df)[c];
    } else {
#pragma unroll
        for (int n = 0; n < NST; ++n) h[n] = 0.f;
    }
    float sumdt = 0.f;
    for (int it = 0; it < CLEN; ++it) {
        int sit = chunk * CLEN + it;
        int l = dir ? (SEQ - 1 - sit) : sit;
        size_t g = (size_t)b * SEQ + l;
        float dt = b2f(DT[g * DI + c]);
        float xc = b2f(XC[g * DI + c]);
        float dtxc = dt * xc;
        const float* bs = &XDP[((size_t)dir * T_TOK + g) * XDP_LD + DTR];
        if (FINAL) {
            float y = 0.f;
#pragma unroll
            for (int n = 0; n < NST; ++n) {
                h[n] = __expf(dt * A[n]) * h[n] + dtxc * bs[n];
                y += h[n] * bs[NST + n];
            }
            YCAT[g * N2 + dir * DI + c] = __float2bfloat16(y + xc * Dv);
        } else {
            sumdt += dt;
#pragma unroll
            for (int n = 0; n < NST; ++n)
                h[n] = __expf(dt * A[n]) * h[n] + dtxc * bs[n];
        }
    }
    if (!FINAL) {
#pragma unroll
        for (int n = 0; n < NST; ++n) HLOC[base * NST + n] = h[n];
        SUMDT[base] = sumdt;
    }
}

// phase B: sequential combine over chunks; rewrites HLOC[k] with carry-in h for chunk k
__global__ __launch_bounds__(256) void scan_combine(float* __restrict__ HLOC,
                                                    const float* __restrict__ SUMDT,
                                                    const float* __restrict__ Af,
                                                    const float* __restrict__ Ab) {
    int idx = blockIdx.x * 256 + threadIdx.x;   // over 2*BATCH*DI*NST = 131072
    int n = idx & 15;
    int c = (idx >> 4) & (DI - 1);
    int b = (idx >> 15) & 1;
    int dir = idx >> 16;
    float A = -__expf((dir ? Ab : Af)[c * NST + n]);
    float h = 0.f;
    for (int k = 0; k < NCHUNK; ++k) {
        size_t base = ((((size_t)dir * BATCH + b) * NCHUNK + k) * DI + c);
        float P = __expf(A * SUMDT[base]);
        float hl = HLOC[base * NST + n];
        HLOC[base * NST + n] = h;
        h = P * h + hl;
    }
}

// ---------------- gating: YM *= silu(z) ----------------
__global__ __launch_bounds__(256) void gate_kernel(bf16* __restrict__ YM, const bf16* __restrict__ XZ) {
    int idx = blockIdx.x * 256 + threadIdx.x;  // over T_TOK*DI
    int t = idx >> 11;
    int c = idx & (DI - 1);
    float z = b2f(XZ[(size_t)t * N2 + DI + c]);
    float y = b2f(YM[idx]);
    YM[idx] = __float2bfloat16(y * (z / (1.f + __expf(-z))));
}

extern "C" void kernel_launch(void* const* d_in, const int* in_sizes, int n_in,
                              void* d_out, int out_size, void* d_ws, size_t ws_size,
                              hipStream_t stream) {
    const float* x       = (const float*)d_in[0];
    const float* gamma   = (const float*)d_in[1];
    const float* beta    = (const float*)d_in[2];
    const float* in_w    = (const float*)d_in[3];
    const float* conv_w  = (const float*)d_in[4];
    const float* conv_b  = (const float*)d_in[5];
    const float* xproj_w = (const float*)d_in[6];
    const float* dt_w    = (const float*)d_in[7];
    const float* dt_b    = (const float*)d_in[8];
    const float* A_log   = (const float*)d_in[9];
    const float* D_skip  = (const float*)d_in[10];
    const float* conv_w_b  = (const float*)d_in[11];
    const float* conv_b_b  = (const float*)d_in[12];
    const float* xproj_w_b = (const float*)d_in[13];
    const float* dt_w_b    = (const float*)d_in[14];
    const float* dt_b_b    = (const float*)d_in[15];
    const float* A_log_b   = (const float*)d_in[16];
    const float* D_skip_b  = (const float*)d_in[17];
    const float* merge_w   = (const float*)d_in[18];
    const float* out_w     = (const float*)d_in[19];
    float* out = (float*)d_out;

    // ---- workspace layout ----
    char* w = (char*)d_ws;
    size_t off = 0;
    bf16* H    = (bf16*)(w + off); off += (size_t)T_TOK * DM * 2;        //  4.19 MB
    bf16* XZ   = (bf16*)(w + off); off += (size_t)T_TOK * N2 * 2;        // 16.78 MB
    bf16* XCF  = (bf16*)(w + off); off += (size_t)T_TOK * DI * 2;        //  8.39 MB
    bf16* XCB  = (bf16*)(w + off); off += (size_t)T_TOK * DI * 2;        //  8.39 MB (contiguous after XCF)
    bf16* XPF  = (bf16*)(w + off); off += (size_t)XDP_LD * DI * 2;       //  0.52 MB
    bf16* XPB  = (bf16*)(w + off); off += (size_t)XDP_LD * DI * 2;       //  0.52 MB
    float* XDP = (float*)(w + off); off += (size_t)2 * T_TOK * XDP_LD * 4; // 4.19 MB  [dir][t][128]
    bf16* DTF  = (bf16*)(w + off); off += (size_t)T_TOK * DI * 2;        //  8.39 MB
    bf16* DTB  = (bf16*)(w + off); off += (size_t)T_TOK * DI * 2;        //  8.39 MB
    bf16* YCAT = (bf16*)(w + off); off += (size_t)T_TOK * N2 * 2;        // 16.78 MB
    bf16* in_wT = (bf16*)(w + off); off += (size_t)N2 * DM * 2;          //  8.39 MB
    float* SUMDT = (float*)(w + off); off += (size_t)2 * BATCH * NCHUNK * DI * 4; // 0.52 MB
    // aliases (stream-ordered, no overlap of live ranges):
    bf16* out_wT   = H;                 // written after gemm1 (last reader of H)
    float* HLOC    = (float*)in_wT;     // written after gemm1 (last reader of in_wT); 8.39 MB exactly
    bf16* merge_wT = XCF;               // written after scan phase C (last reader of XC); spans XCF+XCB = 16.78 MB
    bf16* YM       = DTF;               // written after scan phase C (last reader of DTF)

    // 1. weight prep: in_wT = bf16(in_w^T) [4096][1024]
    transpose_cvt<<<dim3(N2 / 32, DM / 32), dim3(32, 8), 0, stream>>>(in_w, in_wT, DM, N2);
    // 2. xproj prep (pad to 128, transpose, bf16)
    xproj_prep<<<(2 * XDP_LD * DI) / 256, 256, 0, stream>>>(xproj_w, xproj_w_b, XPF, XPB);
    // 3. LayerNorm
    ln_kernel<<<T_TOK, 256, 0, stream>>>(x, gamma, beta, H);
    // 4. xz = H @ in_w  (M=2048, N=4096, K=1024) -> XZ bf16
    mfma_gemm<0><<<dim3(N2 / 128, T_TOK / 128), 256, 0, stream>>>(
        H, in_wT, in_wT, 1 << 30, XZ, nullptr, nullptr, T_TOK, N2, DM);
    // 5. out_wT = bf16(out_w^T) [1024][2048]  (aliases H, safe after step 4)
    transpose_cvt<<<dim3(DM / 32, DI / 32), dim3(32, 8), 0, stream>>>(out_w, out_wT, DI, DM);
    // 6. depthwise conv + silu, both dirs
    conv_kernel<<<(T_TOK * DI) / 256, 256, 0, stream>>>(XZ, conv_w, conv_b, conv_w_b, conv_b_b, XCF, XCB);
    // 7. x_dbl (padded): XDP = [XCF;XCB] @ xproj (M=4096, N=128, K=2048), B per dir
    mfma_gemm<2><<<dim3(1, (2 * T_TOK) / 128), 256, 0, stream>>>(
        XCF, XPF, XPB, (T_TOK / 128), nullptr, nullptr, XDP, 2 * T_TOK, XDP_LD, DI);
    // 8. dt = softplus(x_dbl[:, :64] @ dt_w + dt_b) -> bf16
    gemm_dt<<<dim3(DI / 64, T_TOK / 64), 256, 0, stream>>>(XDP, dt_w, dt_b, DTF, T_TOK, DI);
    gemm_dt<<<dim3(DI / 64, T_TOK / 64), 256, 0, stream>>>(XDP + (size_t)T_TOK * XDP_LD, dt_w_b, dt_b_b, DTB, T_TOK, DI);
    // 9. scan phase A: chunk-local
    scan_chunk<false><<<dim3(DI / 256, BATCH, 2 * NCHUNK), 256, 0, stream>>>(
        DTF, DTB, XCF, XCB, XDP, A_log, A_log_b, D_skip, D_skip_b, HLOC, SUMDT, YCAT);
    // 10. scan phase B: combine
    scan_combine<<<(2 * BATCH * DI * NST) / 256, 256, 0, stream>>>(HLOC, SUMDT, A_log, A_log_b);
    // 11. scan phase C: final with carry-in, emit YCAT
    scan_chunk<true><<<dim3(DI / 256, BATCH, 2 * NCHUNK), 256, 0, stream>>>(
        DTF, DTB, XCF, XCB, XDP, A_log, A_log_b, D_skip, D_skip_b, HLOC, SUMDT, YCAT);
    // 12. merge_wT = bf16(merge_w^T) [2048][4096] (aliases XCF/XCB, safe after step 11)
    transpose_cvt<<<dim3(DI / 32, N2 / 32), dim3(32, 8), 0, stream>>>(merge_w, merge_wT, N2, DI);
    // 13. YM = YCAT @ merge_w (M=2048, N=2048, K=4096) -> bf16 (aliases DTF)
    mfma_gemm<0><<<dim3(DI / 128, T_TOK / 128), 256, 0, stream>>>(
        YCAT, merge_wT, merge_wT, 1 << 30, YM, nullptr, nullptr, T_TOK, DI, N2);
    // 14. YM *= silu(z)
    gate_kernel<<<(T_TOK * DI) / 256, 256, 0, stream>>>(YM, XZ);
    // 15. out = x + YM @ out_w (M=2048, N=1024, K=2048), f32
    mfma_gemm<1><<<dim3(DM / 128, T_TOK / 128), 256, 0, stream>>>(
        YM, out_wT, out_wT, 1 << 30, nullptr, x, out, T_TOK, DM, DI);
}

// Round 4
// 509.396 us; speedup vs baseline: 3.8914x; 1.1796x over previous
//
#include <hip/hip_runtime.h>
#include <hip/hip_bf16.h>
#include <math.h>

typedef __hip_bfloat16 bf16;
typedef unsigned int u32;
typedef __attribute__((ext_vector_type(8))) short bf16x8;
typedef __attribute__((ext_vector_type(4))) float f32x4;

#define BATCH 2
#define SEQ 1024
#define DM 1024
#define DI 2048
#define NST 16
#define DTR 64
#define XDN 96          // dt_rank + 2*N = 64+32
#define XDP_LD 128      // padded x_dbl row
#define T_TOK 2048      // BATCH*SEQ
#define N2 4096         // 2*DI
#define NCHUNK 16
#define CLEN 64

static __device__ __forceinline__ float b2f(bf16 v) { return __bfloat162float(v); }

// ---- async global->LDS, 16 bytes per lane; LDS dest must be wave-uniform base ----
static __device__ __forceinline__ void gload_lds16(const void* g, void* l) {
    __builtin_amdgcn_global_load_lds((__attribute__((address_space(1))) u32*)(size_t)g,
                                     (__attribute__((address_space(3))) u32*)l, 16, 0, 0);
}

// ---------------- LayerNorm: x(f32, T x DM) -> H(bf16) ----------------
__global__ __launch_bounds__(256) void ln_kernel(const float* __restrict__ x,
                                                 const float* __restrict__ gamma,
                                                 const float* __restrict__ beta,
                                                 bf16* __restrict__ H) {
    int t = blockIdx.x;
    int tid = threadIdx.x;
    float xv[4];
    float s = 0.f, s2 = 0.f;
#pragma unroll
    for (int k = 0; k < 4; ++k) {
        float v = x[(size_t)t * DM + k * 256 + tid];
        xv[k] = v; s += v; s2 += v * v;
    }
#pragma unroll
    for (int off = 32; off; off >>= 1) {
        s  += __shfl_down(s, off);
        s2 += __shfl_down(s2, off);
    }
    __shared__ float red[8];
    int wid = tid >> 6, lane = tid & 63;
    if (!lane) { red[wid] = s; red[4 + wid] = s2; }
    __syncthreads();
    if (tid == 0) {
        float S = red[0] + red[1] + red[2] + red[3];
        float S2 = red[4] + red[5] + red[6] + red[7];
        float mu = S * (1.f / DM);
        float var = S2 * (1.f / DM) - mu * mu;
        red[0] = mu;
        red[1] = rsqrtf(var + 1e-5f);
    }
    __syncthreads();
    float mu = red[0], rs = red[1];
#pragma unroll
    for (int k = 0; k < 4; ++k) {
        int i = k * 256 + tid;
        H[(size_t)t * DM + i] = __float2bfloat16((xv[k] - mu) * rs * gamma[i] + beta[i]);
    }
}

// ---------------- weight prep: fp32 [K][N] -> bf16 [N][K] (transpose + convert) ----------------
__global__ __launch_bounds__(256) void transpose_cvt(const float* __restrict__ in,
                                                     bf16* __restrict__ out, int K, int N) {
    __shared__ float t[32][33];
    int bx = blockIdx.x * 32;  // N base
    int by = blockIdx.y * 32;  // K base
    int tx = threadIdx.x;
    for (int r = threadIdx.y; r < 32; r += 8)
        t[r][tx] = in[(size_t)(by + r) * N + bx + tx];
    __syncthreads();
    for (int r = threadIdx.y; r < 32; r += 8)
        out[(size_t)(bx + r) * K + by + tx] = __float2bfloat16(t[tx][r]);
}

// ---------------- xproj prep: fp32 [2048][96] -> bf16 [128][2048], rows >=96 zero ----------------
__global__ __launch_bounds__(256) void xproj_prep(const float* __restrict__ xf,
                                                  const float* __restrict__ xb,
                                                  bf16* __restrict__ XPF, bf16* __restrict__ XPB) {
    int idx = blockIdx.x * 256 + threadIdx.x;   // over 2*128*2048
    int dir = idx >= XDP_LD * DI;
    int i = idx - dir * (XDP_LD * DI);
    int n = i >> 11;
    int k = i & (DI - 1);
    float v = (n < XDN) ? (dir ? xb : xf)[k * XDN + n] : 0.f;
    (dir ? XPB : XPF)[i] = __float2bfloat16(v);
}

// ---------------- MFMA GEMM: C(MxN) = A(MxK,bf16,row-major) * BT(NxK,bf16)^T ----------------
// 128x128 tile, BK=64, 4 waves each 64x64 (4x4 of 16x16x32 MFMA)
// split-K over gridDim.z (K % (64*gridDim.z) == 0)
// EPI 0: bf16 store to Cb;  EPI 1: outf = resid + acc (f32);  EPI 2: f32 store to outf
// EPI 3: fp32 partial store to Pf + blockIdx.z*M*N
template <int EPI>
__global__ __launch_bounds__(256) void mfma_gemm(const bf16* __restrict__ A,
                                                 const bf16* __restrict__ BT,
                                                 const bf16* __restrict__ BT2, int bysplit,
                                                 bf16* __restrict__ Cb,
                                                 const float* __restrict__ resid,
                                                 float* __restrict__ outf,
                                                 float* __restrict__ Pf,
                                                 int M, int N, int K) {
    __shared__ bf16 As[8192];   // [kg 0..7][m 0..127][8]
    __shared__ bf16 Bs[8192];   // [kg 0..7][n 0..127][8]
    int tid = threadIdx.x;
    int wave = tid >> 6, lane = tid & 63;
    int q = lane >> 4, ln16 = lane & 15;
    int bm = blockIdx.y * 128, bn = blockIdx.x * 128;
    int wm = (wave >> 1) * 64, wn = (wave & 1) * 64;
    const bf16* Bt = ((int)blockIdx.y < bysplit) ? BT : BT2;

    int ks = K / gridDim.z;
    int kb = blockIdx.z * ks;

    f32x4 zf; zf[0] = zf[1] = zf[2] = zf[3] = 0.f;
    f32x4 acc[4][4];
#pragma unroll
    for (int i = 0; i < 4; ++i)
#pragma unroll
        for (int j = 0; j < 4; ++j) acc[i][j] = zf;

    for (int k0 = kb; k0 < kb + ks; k0 += 64) {
#pragma unroll
        for (int i = 0; i < 4; ++i) {
            int s = wave * 256 + i * 64 + lane;   // slot 0..1023
            int kg = s >> 7, m = s & 127;
            gload_lds16(&A[(size_t)(bm + m) * K + k0 + kg * 8], &As[(wave * 256 + i * 64) * 8]);
            gload_lds16(&Bt[(size_t)(bn + m) * K + k0 + kg * 8], &Bs[(wave * 256 + i * 64) * 8]);
        }
        __syncthreads();
#pragma unroll
        for (int kk = 0; kk < 2; ++kk) {
            bf16x8 af[4], bfr[4];
#pragma unroll
            for (int i = 0; i < 4; ++i) {
                af[i]  = *(const bf16x8*)&As[(((kk * 4 + q) * 128) + (wm + i * 16 + ln16)) * 8];
                bfr[i] = *(const bf16x8*)&Bs[(((kk * 4 + q) * 128) + (wn + i * 16 + ln16)) * 8];
            }
#pragma unroll
            for (int i = 0; i < 4; ++i)
#pragma unroll
                for (int j = 0; j < 4; ++j)
                    acc[i][j] = __builtin_amdgcn_mfma_f32_16x16x32_bf16(af[i], bfr[j], acc[i][j], 0, 0, 0);
        }
        __syncthreads();
    }

    size_t pbase = (size_t)blockIdx.z * M * N;
#pragma unroll
    for (int i = 0; i < 4; ++i)
#pragma unroll
        for (int r = 0; r < 4; ++r) {
            int row = bm + wm + i * 16 + q * 4 + r;
#pragma unroll
            for (int j = 0; j < 4; ++j) {
                int col = bn + wn + j * 16 + ln16;
                size_t idx = (size_t)row * N + col;
                float v = acc[i][j][r];
                if (EPI == 0)      Cb[idx] = __float2bfloat16(v);
                else if (EPI == 1) outf[idx] = resid[idx] + v;
                else if (EPI == 2) outf[idx] = v;
                else               Pf[pbase + idx] = v;
            }
        }
}

// ---------------- split-K reduce kernels ----------------
// YM = bf16( (sum_s P[s]) * silu(z) )   (fuses gate)
__global__ __launch_bounds__(256) void reduce_gate(const float* __restrict__ P, int ns, size_t MN,
                                                   const bf16* __restrict__ XZ, bf16* __restrict__ YM) {
    size_t i = ((size_t)blockIdx.x * 256 + threadIdx.x) * 4;  // over T_TOK*DI
    float4 s = *reinterpret_cast<const float4*>(&P[i]);
    for (int k = 1; k < ns; ++k) {
        float4 p = *reinterpret_cast<const float4*>(&P[(size_t)k * MN + i]);
        s.x += p.x; s.y += p.y; s.z += p.z; s.w += p.w;
    }
    int t = (int)(i >> 11), c = (int)(i & (DI - 1));
    const bf16* zp = &XZ[(size_t)t * N2 + DI + c];
    float sv[4] = {s.x, s.y, s.z, s.w};
    bf16 r[4];
#pragma unroll
    for (int j = 0; j < 4; ++j) {
        float z = b2f(zp[j]);
        r[j] = __float2bfloat16(sv[j] * (z / (1.f + __expf(-z))));
    }
    *reinterpret_cast<ushort4*>(&YM[i]) = *reinterpret_cast<ushort4*>(r);
}

// out = x + sum_s P[s]
__global__ __launch_bounds__(256) void reduce_out(const float* __restrict__ P, int ns, size_t MN,
                                                  const float* __restrict__ x, float* __restrict__ out) {
    size_t i = ((size_t)blockIdx.x * 256 + threadIdx.x) * 4;  // over T_TOK*DM
    float4 s = *reinterpret_cast<const float4*>(&P[i]);
    for (int k = 1; k < ns; ++k) {
        float4 p = *reinterpret_cast<const float4*>(&P[(size_t)k * MN + i]);
        s.x += p.x; s.y += p.y; s.z += p.z; s.w += p.w;
    }
    float4 xv = *reinterpret_cast<const float4*>(&x[i]);
    s.x += xv.x; s.y += xv.y; s.z += xv.z; s.w += xv.w;
    *reinterpret_cast<float4*>(&out[i]) = s;
}

// XDP = sum_s P[s]
__global__ __launch_bounds__(256) void reduce_xdbl(const float* __restrict__ P, int ns, size_t MN,
                                                   float* __restrict__ XDP) {
    size_t i = ((size_t)blockIdx.x * 256 + threadIdx.x) * 4;  // over 2*T_TOK*128
    float4 s = *reinterpret_cast<const float4*>(&P[i]);
    for (int k = 1; k < ns; ++k) {
        float4 p = *reinterpret_cast<const float4*>(&P[(size_t)k * MN + i]);
        s.x += p.x; s.y += p.y; s.z += p.z; s.w += p.w;
    }
    *reinterpret_cast<float4*>(&XDP[i]) = s;
}

// ---------------- dt GEMM (vector, K=64): DT = softplus(XDP[:, :64] @ dt_w + dt_b) -> bf16 ----------------
__global__ __launch_bounds__(256) void gemm_dt(const float* __restrict__ A,   // lda=128
                                               const float* __restrict__ Bw,  // 64 x 2048 f32
                                               const float* __restrict__ bias,
                                               bf16* __restrict__ Cb, int M, int N) {
    __shared__ float As[16][68];
    __shared__ float Bs[16][68];
    int tid = threadIdx.x;
    int bm = blockIdx.y * 64, bn = blockIdx.x * 64;
    int tx = tid & 15, ty = tid >> 4;
    float acc[4][4];
#pragma unroll
    for (int i = 0; i < 4; ++i)
#pragma unroll
        for (int j = 0; j < 4; ++j) acc[i][j] = 0.f;
    int arow = tid >> 2, acg = (tid & 3) * 4;
    int brow = tid >> 4, bcol = (tid & 15) * 4;
    for (int k0 = 0; k0 < DTR; k0 += 16) {
        float4 av = *reinterpret_cast<const float4*>(&A[(size_t)(bm + arow) * XDP_LD + k0 + acg]);
        As[acg + 0][arow] = av.x; As[acg + 1][arow] = av.y;
        As[acg + 2][arow] = av.z; As[acg + 3][arow] = av.w;
        float4 bv = *reinterpret_cast<const float4*>(&Bw[(size_t)(k0 + brow) * N + bn + bcol]);
        Bs[brow][bcol + 0] = bv.x; Bs[brow][bcol + 1] = bv.y;
        Bs[brow][bcol + 2] = bv.z; Bs[brow][bcol + 3] = bv.w;
        __syncthreads();
#pragma unroll
        for (int kk = 0; kk < 16; ++kk) {
            float4 a = *reinterpret_cast<const float4*>(&As[kk][ty * 4]);
            float4 b = *reinterpret_cast<const float4*>(&Bs[kk][tx * 4]);
            acc[0][0] += a.x * b.x; acc[0][1] += a.x * b.y; acc[0][2] += a.x * b.z; acc[0][3] += a.x * b.w;
            acc[1][0] += a.y * b.x; acc[1][1] += a.y * b.y; acc[1][2] += a.y * b.z; acc[1][3] += a.y * b.w;
            acc[2][0] += a.z * b.x; acc[2][1] += a.z * b.y; acc[2][2] += a.z * b.z; acc[2][3] += a.z * b.w;
            acc[3][0] += a.w * b.x; acc[3][1] += a.w * b.y; acc[3][2] += a.w * b.z; acc[3][3] += a.w * b.w;
        }
        __syncthreads();
    }
    int row0 = bm + ty * 4, col0 = bn + tx * 4;
#pragma unroll
    for (int i = 0; i < 4; ++i)
#pragma unroll
        for (int j = 0; j < 4; ++j) {
            float v = acc[i][j] + bias[col0 + j];
            float sp = (v > 20.f) ? v : log1pf(__expf(v));
            Cb[(size_t)(row0 + i) * N + col0 + j] = __float2bfloat16(sp);
        }
}

// ---------------- depthwise causal conv (fwd) + anti-causal (bwd) + SiLU ----------------
__global__ __launch_bounds__(256) void conv_kernel(const bf16* __restrict__ XZ,
                                                   const float* __restrict__ wf, const float* __restrict__ bf_,
                                                   const float* __restrict__ wb, const float* __restrict__ bb_,
                                                   bf16* __restrict__ XCF, bf16* __restrict__ XCB) {
    int idx = blockIdx.x * 256 + threadIdx.x;   // over T_TOK*DI
    int c = idx & (DI - 1);
    int g = idx >> 11;
    int l = g & (SEQ - 1);
    int b = g >> 10;
    float sf = bf_[c];
    float sb = bb_[c];
#pragma unroll
    for (int j = 0; j < 4; ++j) {
        int lf = l - 3 + j;
        if (lf >= 0) sf += wf[c * 4 + j] * b2f(XZ[((size_t)(b * SEQ + lf)) * N2 + c]);
        int lb = l + 3 - j;
        if (lb < SEQ) sb += wb[c * 4 + j] * b2f(XZ[((size_t)(b * SEQ + lb)) * N2 + c]);
    }
    XCF[idx] = __float2bfloat16(sf / (1.f + __expf(-sf)));
    XCB[idx] = __float2bfloat16(sb / (1.f + __expf(-sb)));
}

// ---------------- chunked selective scan ----------------
template <bool FINAL>
__global__ __launch_bounds__(256) void scan_chunk(const bf16* __restrict__ DTF_, const bf16* __restrict__ DTB_,
                                                  const bf16* __restrict__ XCF_, const bf16* __restrict__ XCB_,
                                                  const float* __restrict__ XDP,
                                                  const float* __restrict__ Af, const float* __restrict__ Ab,
                                                  const float* __restrict__ Df, const float* __restrict__ Db,
                                                  float* __restrict__ HLOC, float* __restrict__ SUMDT,
                                                  bf16* __restrict__ YCAT) {
    int c = blockIdx.x * 256 + threadIdx.x;
    int b = blockIdx.y;
    int dir = blockIdx.z >> 4, chunk = blockIdx.z & 15;
    const bf16* DT = dir ? DTB_ : DTF_;
    const bf16* XC = dir ? XCB_ : XCF_;
    const float* Al = dir ? Ab : Af;
    float A[NST];
#pragma unroll
    for (int n = 0; n < NST; ++n) A[n] = -__expf(Al[c * NST + n]);
    size_t base = ((((size_t)dir * BATCH + b) * NCHUNK + chunk) * DI + c);
    float h[NST];
    float Dv = 0.f;
    if (FINAL) {
#pragma unroll
        for (int n = 0; n < NST; ++n) h[n] = HLOC[base * NST + n];
        Dv = (dir ? Db : Df)[c];
    } else {
#pragma unroll
        for (int n = 0; n < NST; ++n) h[n] = 0.f;
    }
    float sumdt = 0.f;
    for (int it = 0; it < CLEN; ++it) {
        int sit = chunk * CLEN + it;
        int l = dir ? (SEQ - 1 - sit) : sit;
        size_t g = (size_t)b * SEQ + l;
        float dt = b2f(DT[g * DI + c]);
        float xc = b2f(XC[g * DI + c]);
        float dtxc = dt * xc;
        const float* bs = &XDP[((size_t)dir * T_TOK + g) * XDP_LD + DTR];
        if (FINAL) {
            float y = 0.f;
#pragma unroll
            for (int n = 0; n < NST; ++n) {
                h[n] = __expf(dt * A[n]) * h[n] + dtxc * bs[n];
                y += h[n] * bs[NST + n];
            }
            YCAT[g * N2 + dir * DI + c] = __float2bfloat16(y + xc * Dv);
        } else {
            sumdt += dt;
#pragma unroll
            for (int n = 0; n < NST; ++n)
                h[n] = __expf(dt * A[n]) * h[n] + dtxc * bs[n];
        }
    }
    if (!FINAL) {
#pragma unroll
        for (int n = 0; n < NST; ++n) HLOC[base * NST + n] = h[n];
        SUMDT[base] = sumdt;
    }
}

// phase B: sequential combine over chunks; rewrites HLOC[k] with carry-in h for chunk k
__global__ __launch_bounds__(256) void scan_combine(float* __restrict__ HLOC,
                                                    const float* __restrict__ SUMDT,
                                                    const float* __restrict__ Af,
                                                    const float* __restrict__ Ab) {
    int idx = blockIdx.x * 256 + threadIdx.x;   // over 2*BATCH*DI*NST = 131072
    int n = idx & 15;
    int c = (idx >> 4) & (DI - 1);
    int b = (idx >> 15) & 1;
    int dir = idx >> 16;
    float A = -__expf((dir ? Ab : Af)[c * NST + n]);
    float h = 0.f;
    for (int k = 0; k < NCHUNK; ++k) {
        size_t base = ((((size_t)dir * BATCH + b) * NCHUNK + k) * DI + c);
        float P = __expf(A * SUMDT[base]);
        float hl = HLOC[base * NST + n];
        HLOC[base * NST + n] = h;
        h = P * h + hl;
    }
}

// ---------------- gating: YM *= silu(z)  (fallback path when merge not split) ----------------
__global__ __launch_bounds__(256) void gate_kernel(bf16* __restrict__ YM, const bf16* __restrict__ XZ) {
    int idx = blockIdx.x * 256 + threadIdx.x;  // over T_TOK*DI
    int t = idx >> 11;
    int c = idx & (DI - 1);
    float z = b2f(XZ[(size_t)t * N2 + DI + c]);
    float y = b2f(YM[idx]);
    YM[idx] = __float2bfloat16(y * (z / (1.f + __expf(-z))));
}

extern "C" void kernel_launch(void* const* d_in, const int* in_sizes, int n_in,
                              void* d_out, int out_size, void* d_ws, size_t ws_size,
                              hipStream_t stream) {
    const float* x       = (const float*)d_in[0];
    const float* gamma   = (const float*)d_in[1];
    const float* beta    = (const float*)d_in[2];
    const float* in_w    = (const float*)d_in[3];
    const float* conv_w  = (const float*)d_in[4];
    const float* conv_b  = (const float*)d_in[5];
    const float* xproj_w = (const float*)d_in[6];
    const float* dt_w    = (const float*)d_in[7];
    const float* dt_b    = (const float*)d_in[8];
    const float* A_log   = (const float*)d_in[9];
    const float* D_skip  = (const float*)d_in[10];
    const float* conv_w_b  = (const float*)d_in[11];
    const float* conv_b_b  = (const float*)d_in[12];
    const float* xproj_w_b = (const float*)d_in[13];
    const float* dt_w_b    = (const float*)d_in[14];
    const float* dt_b_b    = (const float*)d_in[15];
    const float* A_log_b   = (const float*)d_in[16];
    const float* D_skip_b  = (const float*)d_in[17];
    const float* merge_w   = (const float*)d_in[18];
    const float* out_w     = (const float*)d_in[19];
    float* out = (float*)d_out;

    // ---- base workspace layout ----
    char* w = (char*)d_ws;
    size_t off = 0;
    bf16* H    = (bf16*)(w + off); off += (size_t)T_TOK * DM * 2;        //  4.19 MB
    bf16* XZ   = (bf16*)(w + off); off += (size_t)T_TOK * N2 * 2;        // 16.78 MB
    bf16* XCF  = (bf16*)(w + off); off += (size_t)T_TOK * DI * 2;        //  8.39 MB
    bf16* XCB  = (bf16*)(w + off); off += (size_t)T_TOK * DI * 2;        //  8.39 MB (contiguous after XCF)
    bf16* XPF  = (bf16*)(w + off); off += (size_t)XDP_LD * DI * 2;       //  0.52 MB
    bf16* XPB  = (bf16*)(w + off); off += (size_t)XDP_LD * DI * 2;       //  0.52 MB
    float* XDP = (float*)(w + off); off += (size_t)2 * T_TOK * XDP_LD * 4; // 4.19 MB  [dir][t][128]
    bf16* DTF  = (bf16*)(w + off); off += (size_t)T_TOK * DI * 2;        //  8.39 MB
    bf16* DTB  = (bf16*)(w + off); off += (size_t)T_TOK * DI * 2;        //  8.39 MB
    bf16* YCAT = (bf16*)(w + off); off += (size_t)T_TOK * N2 * 2;        // 16.78 MB
    // PART region: time-shared by in_wT -> xdbl partials -> HLOC+SUMDT -> merge partials -> out partials
    char* PART = w + off;
    size_t avail = (ws_size > off) ? ws_size - off : 0;

    bf16* in_wT  = (bf16*)PART;                    // live: step1 .. step4  (8.39 MB)
    float* HLOC  = (float*)PART;                   // live: scanA .. scanC  (8.39 MB)
    float* SUMDT = (float*)(PART + (size_t)2 * BATCH * NCHUNK * DI * NST * 4); // +0.52 MB
    float* Pf    = (float*)PART;                   // split-K partials
    // aliases outside PART:
    bf16* out_wT   = H;      // written after gemm1 (last reader of H)
    bf16* merge_wT = XCF;    // written after scan C (spans XCF+XCB = 16.78 MB)
    bf16* YM       = DTF;    // written after scan C

    size_t MNm = (size_t)T_TOK * DI;       // merge partial elems (16.78 MB fp32 each)
    size_t MNo = (size_t)T_TOK * DM;       // out partial elems   ( 8.39 MB fp32 each)
    size_t MNx = (size_t)2 * T_TOK * XDP_LD; // xdbl partial elems ( 2.10 MB fp32 each)
    int s_merge = (avail >= 4 * MNm * 4) ? 4 : (avail >= 2 * MNm * 4) ? 2 : (avail >= MNm * 4) ? 1 : 0;
    int s_out   = (avail >= 4 * MNo * 4) ? 4 : (avail >= 2 * MNo * 4) ? 2 : 0;
    int s_xdbl  = (avail >= 16 * MNx * 4) ? 16 : (avail >= 8 * MNx * 4) ? 8 : (avail >= 4 * MNx * 4) ? 4 : 0;

    // 1. weight prep: in_wT = bf16(in_w^T) [4096][1024]
    transpose_cvt<<<dim3(N2 / 32, DM / 32), dim3(32, 8), 0, stream>>>(in_w, in_wT, DM, N2);
    // 2. xproj prep (pad to 128, transpose, bf16)
    xproj_prep<<<(2 * XDP_LD * DI) / 256, 256, 0, stream>>>(xproj_w, xproj_w_b, XPF, XPB);
    // 3. LayerNorm
    ln_kernel<<<T_TOK, 256, 0, stream>>>(x, gamma, beta, H);
    // 4. xz = H @ in_w  (M=2048, N=4096, K=1024) -> XZ bf16   [512 blocks, no split]
    mfma_gemm<0><<<dim3(N2 / 128, T_TOK / 128), 256, 0, stream>>>(
        H, in_wT, in_wT, 1 << 30, XZ, nullptr, nullptr, nullptr, T_TOK, N2, DM);
    // 5. out_wT = bf16(out_w^T) [1024][2048]  (aliases H, safe after step 4)
    transpose_cvt<<<dim3(DM / 32, DI / 32), dim3(32, 8), 0, stream>>>(out_w, out_wT, DI, DM);
    // 6. depthwise conv + silu, both dirs
    conv_kernel<<<(T_TOK * DI) / 256, 256, 0, stream>>>(XZ, conv_w, conv_b, conv_w_b, conv_b_b, XCF, XCB);
    // 7. x_dbl (padded): XDP = [XCF;XCB] @ xproj (M=4096, N=128, K=2048), B per dir
    if (s_xdbl) {
        mfma_gemm<3><<<dim3(1, (2 * T_TOK) / 128, s_xdbl), 256, 0, stream>>>(
            XCF, XPF, XPB, (T_TOK / 128), nullptr, nullptr, nullptr, Pf, 2 * T_TOK, XDP_LD, DI);
        reduce_xdbl<<<(int)(MNx / 4 / 256), 256, 0, stream>>>(Pf, s_xdbl, MNx, XDP);
    } else {
        mfma_gemm<2><<<dim3(1, (2 * T_TOK) / 128), 256, 0, stream>>>(
            XCF, XPF, XPB, (T_TOK / 128), nullptr, nullptr, XDP, nullptr, 2 * T_TOK, XDP_LD, DI);
    }
    // 8. dt = softplus(x_dbl[:, :64] @ dt_w + dt_b) -> bf16
    gemm_dt<<<dim3(DI / 64, T_TOK / 64), 256, 0, stream>>>(XDP, dt_w, dt_b, DTF, T_TOK, DI);
    gemm_dt<<<dim3(DI / 64, T_TOK / 64), 256, 0, stream>>>(XDP + (size_t)T_TOK * XDP_LD, dt_w_b, dt_b_b, DTB, T_TOK, DI);
    // 9-11. chunked scan (HLOC/SUMDT live in PART; xdbl partials dead by now)
    scan_chunk<false><<<dim3(DI / 256, BATCH, 2 * NCHUNK), 256, 0, stream>>>(
        DTF, DTB, XCF, XCB, XDP, A_log, A_log_b, D_skip, D_skip_b, HLOC, SUMDT, YCAT);
    scan_combine<<<(2 * BATCH * DI * NST) / 256, 256, 0, stream>>>(HLOC, SUMDT, A_log, A_log_b);
    scan_chunk<true><<<dim3(DI / 256, BATCH, 2 * NCHUNK), 256, 0, stream>>>(
        DTF, DTB, XCF, XCB, XDP, A_log, A_log_b, D_skip, D_skip_b, HLOC, SUMDT, YCAT);
    // 12. merge_wT = bf16(merge_w^T) [2048][4096] (aliases XCF/XCB, safe after scan C)
    transpose_cvt<<<dim3(DI / 32, N2 / 32), dim3(32, 8), 0, stream>>>(merge_w, merge_wT, N2, DI);
    // 13. YM = silu(z) * (YCAT @ merge_w) (M=2048, N=2048, K=4096)
    if (s_merge) {
        mfma_gemm<3><<<dim3(DI / 128, T_TOK / 128, s_merge), 256, 0, stream>>>(
            YCAT, merge_wT, merge_wT, 1 << 30, nullptr, nullptr, nullptr, Pf, T_TOK, DI, N2);
        reduce_gate<<<(int)(MNm / 4 / 256), 256, 0, stream>>>(Pf, s_merge, MNm, XZ, YM);
    } else {
        mfma_gemm<0><<<dim3(DI / 128, T_TOK / 128), 256, 0, stream>>>(
            YCAT, merge_wT, merge_wT, 1 << 30, YM, nullptr, nullptr, nullptr, T_TOK, DI, N2);
        gate_kernel<<<(T_TOK * DI) / 256, 256, 0, stream>>>(YM, XZ);
    }
    // 14. out = x + YM @ out_w (M=2048, N=1024, K=2048), f32
    if (s_out) {
        mfma_gemm<3><<<dim3(DM / 128, T_TOK / 128, s_out), 256, 0, stream>>>(
            YM, out_wT, out_wT, 1 << 30, nullptr, nullptr, nullptr, Pf, T_TOK, DM, DI);
        reduce_out<<<(int)(MNo / 4 / 256), 256, 0, stream>>>(Pf, s_out, MNo, x, out);
    } else {
        mfma_gemm<1><<<dim3(DM / 128, T_TOK / 128), 256, 0, stream>>>(
            YM, out_wT, out_wT, 1 << 30, nullptr, x, out, nullptr, T_TOK, DM, DI);
    }
}

// Round 5
// 493.195 us; speedup vs baseline: 4.0192x; 1.0328x over previous
//
#include <hip/hip_runtime.h>
#include <hip/hip_bf16.h>
#include <math.h>

typedef __hip_bfloat16 bf16;
typedef unsigned int u32;
typedef __attribute__((ext_vector_type(8))) short bf16x8;
typedef __attribute__((ext_vector_type(4))) float f32x4;

#define BATCH 2
#define SEQ 1024
#define DM 1024
#define DI 2048
#define NST 16
#define DTR 64
#define XDN 96          // dt_rank + 2*N = 64+32
#define XDP_LD 128      // padded x_dbl row
#define T_TOK 2048      // BATCH*SEQ
#define N2 4096         // 2*DI
#define NCHUNK 16
#define CLEN 64

static __device__ __forceinline__ float b2f(bf16 v) { return __bfloat162float(v); }
static __device__ __forceinline__ float bits2f(unsigned short u) {
    return __uint_as_float(((unsigned)u) << 16);
}

// ---- async global->LDS, 16 bytes per lane; LDS dest must be wave-uniform base ----
static __device__ __forceinline__ void gload_lds16(const void* g, void* l) {
    __builtin_amdgcn_global_load_lds((__attribute__((address_space(1))) u32*)(size_t)g,
                                     (__attribute__((address_space(3))) u32*)l, 16, 0, 0);
}

// ---------------- LayerNorm: x(f32, T x DM) -> H(bf16) ----------------
__global__ __launch_bounds__(256) void ln_kernel(const float* __restrict__ x,
                                                 const float* __restrict__ gamma,
                                                 const float* __restrict__ beta,
                                                 bf16* __restrict__ H) {
    int t = blockIdx.x;
    int tid = threadIdx.x;
    float xv[4];
    float s = 0.f, s2 = 0.f;
#pragma unroll
    for (int k = 0; k < 4; ++k) {
        float v = x[(size_t)t * DM + k * 256 + tid];
        xv[k] = v; s += v; s2 += v * v;
    }
#pragma unroll
    for (int off = 32; off; off >>= 1) {
        s  += __shfl_down(s, off);
        s2 += __shfl_down(s2, off);
    }
    __shared__ float red[8];
    int wid = tid >> 6, lane = tid & 63;
    if (!lane) { red[wid] = s; red[4 + wid] = s2; }
    __syncthreads();
    if (tid == 0) {
        float S = red[0] + red[1] + red[2] + red[3];
        float S2 = red[4] + red[5] + red[6] + red[7];
        float mu = S * (1.f / DM);
        float var = S2 * (1.f / DM) - mu * mu;
        red[0] = mu;
        red[1] = rsqrtf(var + 1e-5f);
    }
    __syncthreads();
    float mu = red[0], rs = red[1];
#pragma unroll
    for (int k = 0; k < 4; ++k) {
        int i = k * 256 + tid;
        H[(size_t)t * DM + i] = __float2bfloat16((xv[k] - mu) * rs * gamma[i] + beta[i]);
    }
}

// ---------------- weight prep: fp32 [K][N] -> bf16 [N][K] (transpose + convert) ----------------
__global__ __launch_bounds__(256) void transpose_cvt(const float* __restrict__ in,
                                                     bf16* __restrict__ out, int K, int N) {
    __shared__ float t[32][33];
    int bx = blockIdx.x * 32;  // N base
    int by = blockIdx.y * 32;  // K base
    int tx = threadIdx.x;
    for (int r = threadIdx.y; r < 32; r += 8)
        t[r][tx] = in[(size_t)(by + r) * N + bx + tx];
    __syncthreads();
    for (int r = threadIdx.y; r < 32; r += 8)
        out[(size_t)(bx + r) * K + by + tx] = __float2bfloat16(t[tx][r]);
}

// ---------------- small prep: xproj pad-transpose + dt_w transpose (both dirs) ----------------
// idx < 2*128*2048: xproj; else dt_wT[dir][n*64+k] = dt_w_dir[k*2048+n]
__global__ __launch_bounds__(256) void prep_small(const float* __restrict__ xf,
                                                  const float* __restrict__ xb,
                                                  const float* __restrict__ dtwf,
                                                  const float* __restrict__ dtwb,
                                                  bf16* __restrict__ XPF, bf16* __restrict__ XPB,
                                                  bf16* __restrict__ dtwT) {
    int idx = blockIdx.x * 256 + threadIdx.x;
    if (idx < 2 * XDP_LD * DI) {
        int dir = idx >= XDP_LD * DI;
        int i = idx - dir * (XDP_LD * DI);
        int n = i >> 11;
        int k = i & (DI - 1);
        float v = (n < XDN) ? (dir ? xb : xf)[k * XDN + n] : 0.f;
        (dir ? XPB : XPF)[i] = __float2bfloat16(v);
    } else {
        int j = idx - 2 * XDP_LD * DI;     // over 2*2048*64
        int dir = j >= DI * DTR;
        int e = j - dir * (DI * DTR);
        int n = e >> 6;
        int k = e & 63;
        dtwT[(size_t)dir * DI * DTR + n * DTR + k] =
            __float2bfloat16((dir ? dtwb : dtwf)[(size_t)k * DI + n]);
    }
}

// ---------------- MFMA GEMM: C(MxN) = A(MxK,bf16,row-major) * BT(NxK,bf16)^T ----------------
// 128x128 tile, BK=64, 4 waves each 64x64 (4x4 of 16x16x32 MFMA); split-K over gridDim.z
// EPI 0: bf16 store to Cb
// EPI 1: outf = resid + acc (f32)
// EPI 2: f32 store to outf
// EPI 3: bf16 partial store to Pb + blockIdx.z*M*N
// EPI 4: dt: Cb = bf16(softplus(acc + bias[col])), bias = row<T_TOK ? bias1 : bias2
template <int EPI>
__global__ __launch_bounds__(256) void mfma_gemm(const bf16* __restrict__ A,
                                                 const bf16* __restrict__ BT,
                                                 const bf16* __restrict__ BT2, int bysplit,
                                                 bf16* __restrict__ Cb,
                                                 const float* __restrict__ resid,
                                                 float* __restrict__ outf,
                                                 bf16* __restrict__ Pb,
                                                 const float* __restrict__ bias1,
                                                 const float* __restrict__ bias2,
                                                 int M, int N, int K) {
    __shared__ bf16 As[8192];   // [kg 0..7][m 0..127][8]
    __shared__ bf16 Bs[8192];   // [kg 0..7][n 0..127][8]
    int tid = threadIdx.x;
    int wave = tid >> 6, lane = tid & 63;
    int q = lane >> 4, ln16 = lane & 15;
    int bm = blockIdx.y * 128, bn = blockIdx.x * 128;
    int wm = (wave >> 1) * 64, wn = (wave & 1) * 64;
    const bf16* Bt = ((int)blockIdx.y < bysplit) ? BT : BT2;

    int ks = K / gridDim.z;
    int kb = blockIdx.z * ks;

    f32x4 zf; zf[0] = zf[1] = zf[2] = zf[3] = 0.f;
    f32x4 acc[4][4];
#pragma unroll
    for (int i = 0; i < 4; ++i)
#pragma unroll
        for (int j = 0; j < 4; ++j) acc[i][j] = zf;

    for (int k0 = kb; k0 < kb + ks; k0 += 64) {
#pragma unroll
        for (int i = 0; i < 4; ++i) {
            int s = wave * 256 + i * 64 + lane;   // slot 0..1023
            int kg = s >> 7, m = s & 127;
            gload_lds16(&A[(size_t)(bm + m) * K + k0 + kg * 8], &As[(wave * 256 + i * 64) * 8]);
            gload_lds16(&Bt[(size_t)(bn + m) * K + k0 + kg * 8], &Bs[(wave * 256 + i * 64) * 8]);
        }
        __syncthreads();
#pragma unroll
        for (int kk = 0; kk < 2; ++kk) {
            bf16x8 af[4], bfr[4];
#pragma unroll
            for (int i = 0; i < 4; ++i) {
                af[i]  = *(const bf16x8*)&As[(((kk * 4 + q) * 128) + (wm + i * 16 + ln16)) * 8];
                bfr[i] = *(const bf16x8*)&Bs[(((kk * 4 + q) * 128) + (wn + i * 16 + ln16)) * 8];
            }
#pragma unroll
            for (int i = 0; i < 4; ++i)
#pragma unroll
                for (int j = 0; j < 4; ++j)
                    acc[i][j] = __builtin_amdgcn_mfma_f32_16x16x32_bf16(af[i], bfr[j], acc[i][j], 0, 0, 0);
        }
        __syncthreads();
    }

    size_t pbase = (size_t)blockIdx.z * M * N;
#pragma unroll
    for (int i = 0; i < 4; ++i)
#pragma unroll
        for (int r = 0; r < 4; ++r) {
            int row = bm + wm + i * 16 + q * 4 + r;
            const float* bias = (EPI == 4) ? ((row < T_TOK) ? bias1 : bias2) : nullptr;
#pragma unroll
            for (int j = 0; j < 4; ++j) {
                int col = bn + wn + j * 16 + ln16;
                size_t idx = (size_t)row * N + col;
                float v = acc[i][j][r];
                if (EPI == 0)      Cb[idx] = __float2bfloat16(v);
                else if (EPI == 1) outf[idx] = resid[idx] + v;
                else if (EPI == 2) outf[idx] = v;
                else if (EPI == 3) Pb[pbase + idx] = __float2bfloat16(v);
                else {
                    float t = v + bias[col];
                    float sp = (t > 20.f) ? t : log1pf(__expf(t));
                    Cb[idx] = __float2bfloat16(sp);
                }
            }
        }
}

// ---------------- split-K reduce kernels (bf16 partials) ----------------
// YM = bf16( (sum_s P[s]) * silu(z) )
__global__ __launch_bounds__(256) void reduce_gate(const bf16* __restrict__ P, int ns, size_t MN,
                                                   const bf16* __restrict__ XZ, bf16* __restrict__ YM) {
    size_t i = ((size_t)blockIdx.x * 256 + threadIdx.x) * 4;  // over T_TOK*DI
    float s[4] = {0.f, 0.f, 0.f, 0.f};
    for (int k = 0; k < ns; ++k) {
        ushort4 p = *reinterpret_cast<const ushort4*>(&P[(size_t)k * MN + i]);
        s[0] += bits2f(p.x); s[1] += bits2f(p.y); s[2] += bits2f(p.z); s[3] += bits2f(p.w);
    }
    int t = (int)(i >> 11), c = (int)(i & (DI - 1));
    const bf16* zp = &XZ[(size_t)t * N2 + DI + c];
    bf16 r[4];
#pragma unroll
    for (int j = 0; j < 4; ++j) {
        float z = b2f(zp[j]);
        r[j] = __float2bfloat16(s[j] * (z / (1.f + __expf(-z))));
    }
    *reinterpret_cast<ushort4*>(&YM[i]) = *reinterpret_cast<ushort4*>(r);
}

// out = x + sum_s P[s]
__global__ __launch_bounds__(256) void reduce_out(const bf16* __restrict__ P, int ns, size_t MN,
                                                  const float* __restrict__ x, float* __restrict__ out) {
    size_t i = ((size_t)blockIdx.x * 256 + threadIdx.x) * 4;  // over T_TOK*DM
    float s[4] = {0.f, 0.f, 0.f, 0.f};
    for (int k = 0; k < ns; ++k) {
        ushort4 p = *reinterpret_cast<const ushort4*>(&P[(size_t)k * MN + i]);
        s[0] += bits2f(p.x); s[1] += bits2f(p.y); s[2] += bits2f(p.z); s[3] += bits2f(p.w);
    }
    float4 xv = *reinterpret_cast<const float4*>(&x[i]);
    float4 o = {s[0] + xv.x, s[1] + xv.y, s[2] + xv.z, s[3] + xv.w};
    *reinterpret_cast<float4*>(&out[i]) = o;
}

// XDP = sum_s P[s] (f32); also XDdt bf16 copy of cols 0..63 (A-operand for dt MFMA)
__global__ __launch_bounds__(256) void reduce_xdbl(const bf16* __restrict__ P, int ns, size_t MN,
                                                   float* __restrict__ XDP, bf16* __restrict__ XDdt) {
    size_t i = ((size_t)blockIdx.x * 256 + threadIdx.x) * 4;  // over 2*T_TOK*128
    float s[4] = {0.f, 0.f, 0.f, 0.f};
    for (int k = 0; k < ns; ++k) {
        ushort4 p = *reinterpret_cast<const ushort4*>(&P[(size_t)k * MN + i]);
        s[0] += bits2f(p.x); s[1] += bits2f(p.y); s[2] += bits2f(p.z); s[3] += bits2f(p.w);
    }
    float4 o = {s[0], s[1], s[2], s[3]};
    *reinterpret_cast<float4*>(&XDP[i]) = o;
    int col = (int)(i & (XDP_LD - 1));
    if (col < DTR) {
        size_t row = i >> 7;
        bf16 r[4];
#pragma unroll
        for (int j = 0; j < 4; ++j) r[j] = __float2bfloat16(s[j]);
        *reinterpret_cast<ushort4*>(&XDdt[row * DTR + col]) = *reinterpret_cast<ushort4*>(r);
    }
}

// ---------------- dt GEMM fallback (vector, K=64, reads XDP fp32) ----------------
__global__ __launch_bounds__(256) void gemm_dt(const float* __restrict__ A,   // lda=128
                                               const float* __restrict__ Bw,  // 64 x 2048 f32
                                               const float* __restrict__ bias,
                                               bf16* __restrict__ Cb, int M, int N) {
    __shared__ float As[16][68];
    __shared__ float Bs[16][68];
    int tid = threadIdx.x;
    int bm = blockIdx.y * 64, bn = blockIdx.x * 64;
    int tx = tid & 15, ty = tid >> 4;
    float acc[4][4];
#pragma unroll
    for (int i = 0; i < 4; ++i)
#pragma unroll
        for (int j = 0; j < 4; ++j) acc[i][j] = 0.f;
    int arow = tid >> 2, acg = (tid & 3) * 4;
    int brow = tid >> 4, bcol = (tid & 15) * 4;
    for (int k0 = 0; k0 < DTR; k0 += 16) {
        float4 av = *reinterpret_cast<const float4*>(&A[(size_t)(bm + arow) * XDP_LD + k0 + acg]);
        As[acg + 0][arow] = av.x; As[acg + 1][arow] = av.y;
        As[acg + 2][arow] = av.z; As[acg + 3][arow] = av.w;
        float4 bv = *reinterpret_cast<const float4*>(&Bw[(size_t)(k0 + brow) * N + bn + bcol]);
        Bs[brow][bcol + 0] = bv.x; Bs[brow][bcol + 1] = bv.y;
        Bs[brow][bcol + 2] = bv.z; Bs[brow][bcol + 3] = bv.w;
        __syncthreads();
#pragma unroll
        for (int kk = 0; kk < 16; ++kk) {
            float4 a = *reinterpret_cast<const float4*>(&As[kk][ty * 4]);
            float4 b = *reinterpret_cast<const float4*>(&Bs[kk][tx * 4]);
            acc[0][0] += a.x * b.x; acc[0][1] += a.x * b.y; acc[0][2] += a.x * b.z; acc[0][3] += a.x * b.w;
            acc[1][0] += a.y * b.x; acc[1][1] += a.y * b.y; acc[1][2] += a.y * b.z; acc[1][3] += a.y * b.w;
            acc[2][0] += a.z * b.x; acc[2][1] += a.z * b.y; acc[2][2] += a.z * b.z; acc[2][3] += a.z * b.w;
            acc[3][0] += a.w * b.x; acc[3][1] += a.w * b.y; acc[3][2] += a.w * b.z; acc[3][3] += a.w * b.w;
        }
        __syncthreads();
    }
    int row0 = bm + ty * 4, col0 = bn + tx * 4;
#pragma unroll
    for (int i = 0; i < 4; ++i)
#pragma unroll
        for (int j = 0; j < 4; ++j) {
            float v = acc[i][j] + bias[col0 + j];
            float sp = (v > 20.f) ? v : log1pf(__expf(v));
            Cb[(size_t)(row0 + i) * N + col0 + j] = __float2bfloat16(sp);
        }
}

// ---------------- depthwise causal conv (fwd) + anti-causal (bwd) + SiLU ----------------
__global__ __launch_bounds__(256) void conv_kernel(const bf16* __restrict__ XZ,
                                                   const float* __restrict__ wf, const float* __restrict__ bf_,
                                                   const float* __restrict__ wb, const float* __restrict__ bb_,
                                                   bf16* __restrict__ XCF, bf16* __restrict__ XCB) {
    int idx = blockIdx.x * 256 + threadIdx.x;   // over T_TOK*DI
    int c = idx & (DI - 1);
    int g = idx >> 11;
    int l = g & (SEQ - 1);
    int b = g >> 10;
    float sf = bf_[c];
    float sb = bb_[c];
#pragma unroll
    for (int j = 0; j < 4; ++j) {
        int lf = l - 3 + j;
        if (lf >= 0) sf += wf[c * 4 + j] * b2f(XZ[((size_t)(b * SEQ + lf)) * N2 + c]);
        int lb = l + 3 - j;
        if (lb < SEQ) sb += wb[c * 4 + j] * b2f(XZ[((size_t)(b * SEQ + lb)) * N2 + c]);
    }
    XCF[idx] = __float2bfloat16(sf / (1.f + __expf(-sf)));
    XCB[idx] = __float2bfloat16(sb / (1.f + __expf(-sb)));
}

// ---------------- chunked selective scan ----------------
template <bool FINAL>
__global__ __launch_bounds__(256) void scan_chunk(const bf16* __restrict__ DTF_, const bf16* __restrict__ DTB_,
                                                  const bf16* __restrict__ XCF_, const bf16* __restrict__ XCB_,
                                                  const float* __restrict__ XDP,
                                                  const float* __restrict__ Af, const float* __restrict__ Ab,
                                                  const float* __restrict__ Df, const float* __restrict__ Db,
                                                  float* __restrict__ HLOC, float* __restrict__ SUMDT,
                                                  bf16* __restrict__ YCAT) {
    int c = blockIdx.x * 256 + threadIdx.x;
    int b = blockIdx.y;
    int dir = blockIdx.z >> 4, chunk = blockIdx.z & 15;
    const bf16* DT = dir ? DTB_ : DTF_;
    const bf16* XC = dir ? XCB_ : XCF_;
    const float* Al = dir ? Ab : Af;
    float A[NST];
#pragma unroll
    for (int n = 0; n < NST; ++n) A[n] = -__expf(Al[c * NST + n]);
    size_t base = ((((size_t)dir * BATCH + b) * NCHUNK + chunk) * DI + c);
    float h[NST];
    float Dv = 0.f;
    if (FINAL) {
#pragma unroll
        for (int n = 0; n < NST; ++n) h[n] = HLOC[base * NST + n];
        Dv = (dir ? Db : Df)[c];
    } else {
#pragma unroll
        for (int n = 0; n < NST; ++n) h[n] = 0.f;
    }
    float sumdt = 0.f;
    for (int it = 0; it < CLEN; ++it) {
        int sit = chunk * CLEN + it;
        int l = dir ? (SEQ - 1 - sit) : sit;
        size_t g = (size_t)b * SEQ + l;
        float dt = b2f(DT[g * DI + c]);
        float xc = b2f(XC[g * DI + c]);
        float dtxc = dt * xc;
        const float* bs = &XDP[((size_t)dir * T_TOK + g) * XDP_LD + DTR];
        if (FINAL) {
            float y = 0.f;
#pragma unroll
            for (int n = 0; n < NST; ++n) {
                h[n] = __expf(dt * A[n]) * h[n] + dtxc * bs[n];
                y += h[n] * bs[NST + n];
            }
            YCAT[g * N2 + dir * DI + c] = __float2bfloat16(y + xc * Dv);
        } else {
            sumdt += dt;
#pragma unroll
            for (int n = 0; n < NST; ++n)
                h[n] = __expf(dt * A[n]) * h[n] + dtxc * bs[n];
        }
    }
    if (!FINAL) {
#pragma unroll
        for (int n = 0; n < NST; ++n) HLOC[base * NST + n] = h[n];
        SUMDT[base] = sumdt;
    }
}

// phase B: sequential combine over chunks; rewrites HLOC[k] with carry-in h for chunk k
__global__ __launch_bounds__(256) void scan_combine(float* __restrict__ HLOC,
                                                    const float* __restrict__ SUMDT,
                                                    const float* __restrict__ Af,
                                                    const float* __restrict__ Ab) {
    int idx = blockIdx.x * 256 + threadIdx.x;   // over 2*BATCH*DI*NST = 131072
    int n = idx & 15;
    int c = (idx >> 4) & (DI - 1);
    int b = (idx >> 15) & 1;
    int dir = idx >> 16;
    float A = -__expf((dir ? Ab : Af)[c * NST + n]);
    float h = 0.f;
    for (int k = 0; k < NCHUNK; ++k) {
        size_t base = ((((size_t)dir * BATCH + b) * NCHUNK + k) * DI + c);
        float P = __expf(A * SUMDT[base]);
        float hl = HLOC[base * NST + n];
        HLOC[base * NST + n] = h;
        h = P * h + hl;
    }
}

// ---------------- gating fallback: YM *= silu(z) ----------------
__global__ __launch_bounds__(256) void gate_kernel(bf16* __restrict__ YM, const bf16* __restrict__ XZ) {
    int idx = blockIdx.x * 256 + threadIdx.x;  // over T_TOK*DI
    int t = idx >> 11;
    int c = idx & (DI - 1);
    float z = b2f(XZ[(size_t)t * N2 + DI + c]);
    float y = b2f(YM[idx]);
    YM[idx] = __float2bfloat16(y * (z / (1.f + __expf(-z))));
}

extern "C" void kernel_launch(void* const* d_in, const int* in_sizes, int n_in,
                              void* d_out, int out_size, void* d_ws, size_t ws_size,
                              hipStream_t stream) {
    const float* x       = (const float*)d_in[0];
    const float* gamma   = (const float*)d_in[1];
    const float* beta    = (const float*)d_in[2];
    const float* in_w    = (const float*)d_in[3];
    const float* conv_w  = (const float*)d_in[4];
    const float* conv_b  = (const float*)d_in[5];
    const float* xproj_w = (const float*)d_in[6];
    const float* dt_w    = (const float*)d_in[7];
    const float* dt_b    = (const float*)d_in[8];
    const float* A_log   = (const float*)d_in[9];
    const float* D_skip  = (const float*)d_in[10];
    const float* conv_w_b  = (const float*)d_in[11];
    const float* conv_b_b  = (const float*)d_in[12];
    const float* xproj_w_b = (const float*)d_in[13];
    const float* dt_w_b    = (const float*)d_in[14];
    const float* dt_b_b    = (const float*)d_in[15];
    const float* A_log_b   = (const float*)d_in[16];
    const float* D_skip_b  = (const float*)d_in[17];
    const float* merge_w   = (const float*)d_in[18];
    const float* out_w     = (const float*)d_in[19];
    float* out = (float*)d_out;

    // ---- base workspace layout ----
    char* w = (char*)d_ws;
    size_t off = 0;
    bf16* H     = (bf16*)(w + off); off += (size_t)T_TOK * DM * 2;          //  4.19 MB
    bf16* XZ    = (bf16*)(w + off); off += (size_t)T_TOK * N2 * 2;          // 16.78 MB
    bf16* XCF   = (bf16*)(w + off); off += (size_t)T_TOK * DI * 2;          //  8.39 MB
    bf16* XCB   = (bf16*)(w + off); off += (size_t)T_TOK * DI * 2;          //  8.39 MB
    bf16* XPF   = (bf16*)(w + off); off += (size_t)XDP_LD * DI * 2;         //  0.52 MB
    bf16* XPB   = (bf16*)(w + off); off += (size_t)XDP_LD * DI * 2;         //  0.52 MB
    float* XDP  = (float*)(w + off); off += (size_t)2 * T_TOK * XDP_LD * 4; //  2.10 MB
    bf16* DTF   = (bf16*)(w + off); off += (size_t)T_TOK * DI * 2;          //  8.39 MB
    bf16* DTB   = (bf16*)(w + off); off += (size_t)T_TOK * DI * 2;          //  8.39 MB (contig after DTF)
    bf16* YCAT  = (bf16*)(w + off); off += (size_t)T_TOK * N2 * 2;          // 16.78 MB
    bf16* in_wT = (bf16*)(w + off); off += (size_t)N2 * DM * 2;             //  8.39 MB
    bf16* out_wT= (bf16*)(w + off); off += (size_t)DM * DI * 2;             //  4.19 MB
    bf16* dtwT  = (bf16*)(w + off); off += (size_t)2 * DI * DTR * 2;        //  0.52 MB
    bf16* XDdt  = (bf16*)(w + off); off += (size_t)2 * T_TOK * DTR * 2;     //  0.52 MB
    // PART region: xdbl partials -> HLOC+SUMDT -> merge partials -> out partials
    char* PART = w + off;
    size_t avail = (ws_size > off) ? ws_size - off : 0;

    float* HLOC  = (float*)PART;                                            // 8.39 MB
    float* SUMDT = (float*)(PART + (size_t)2 * BATCH * NCHUNK * DI * NST * 4);
    bf16* Pb     = (bf16*)PART;                                             // split-K bf16 partials
    bf16* merge_wT = XCF;    // written after scan C (spans XCF+XCB = 16.78 MB)
    bf16* YM       = DTF;    // written after scan C

    size_t MNm = (size_t)T_TOK * DI;          // merge partial elems
    size_t MNo = (size_t)T_TOK * DM;          // out partial elems
    size_t MNx = (size_t)2 * T_TOK * XDP_LD;  // xdbl partial elems
    int s_merge = (avail >= 4 * MNm * 2) ? 4 : (avail >= 2 * MNm * 2) ? 2 : 0;
    int s_out   = (avail >= 4 * MNo * 2) ? 4 : (avail >= 2 * MNo * 2) ? 2 : 0;
    int s_xdbl  = (avail >= 16 * MNx * 2) ? 16 : (avail >= 8 * MNx * 2) ? 8 : (avail >= 4 * MNx * 2) ? 4 : 0;

    // 1. weight preps (dedicated buffers, no aliasing hazards)
    transpose_cvt<<<dim3(N2 / 32, DM / 32), dim3(32, 8), 0, stream>>>(in_w, in_wT, DM, N2);
    transpose_cvt<<<dim3(DM / 32, DI / 32), dim3(32, 8), 0, stream>>>(out_w, out_wT, DI, DM);
    prep_small<<<(2 * XDP_LD * DI + 2 * DI * DTR) / 256, 256, 0, stream>>>(
        xproj_w, xproj_w_b, dt_w, dt_w_b, XPF, XPB, dtwT);
    // 2. LayerNorm
    ln_kernel<<<T_TOK, 256, 0, stream>>>(x, gamma, beta, H);
    // 3. xz = H @ in_w  (M=2048, N=4096, K=1024) -> XZ bf16
    mfma_gemm<0><<<dim3(N2 / 128, T_TOK / 128), 256, 0, stream>>>(
        H, in_wT, in_wT, 1 << 30, XZ, nullptr, nullptr, nullptr, nullptr, nullptr, T_TOK, N2, DM);
    // 4. depthwise conv + silu, both dirs
    conv_kernel<<<(T_TOK * DI) / 256, 256, 0, stream>>>(XZ, conv_w, conv_b, conv_w_b, conv_b_b, XCF, XCB);
    // 5. x_dbl (padded): XDP = [XCF;XCB] @ xproj (M=4096, N=128, K=2048), B per dir
    if (s_xdbl) {
        mfma_gemm<3><<<dim3(1, (2 * T_TOK) / 128, s_xdbl), 256, 0, stream>>>(
            XCF, XPF, XPB, (T_TOK / 128), nullptr, nullptr, nullptr, Pb, nullptr, nullptr,
            2 * T_TOK, XDP_LD, DI);
        reduce_xdbl<<<(int)(MNx / 4 / 256), 256, 0, stream>>>(Pb, s_xdbl, MNx, XDP, XDdt);
        // 6. dt = softplus(XDdt @ dt_w + dt_b) via MFMA (M=4096 both dirs, N=2048, K=64)
        mfma_gemm<4><<<dim3(DI / 128, (2 * T_TOK) / 128), 256, 0, stream>>>(
            XDdt, dtwT, dtwT + (size_t)DI * DTR, (T_TOK / 128), DTF, nullptr, nullptr, nullptr,
            dt_b, dt_b_b, 2 * T_TOK, DI, DTR);
    } else {
        mfma_gemm<2><<<dim3(1, (2 * T_TOK) / 128), 256, 0, stream>>>(
            XCF, XPF, XPB, (T_TOK / 128), nullptr, nullptr, XDP, nullptr, nullptr, nullptr,
            2 * T_TOK, XDP_LD, DI);
        gemm_dt<<<dim3(DI / 64, T_TOK / 64), 256, 0, stream>>>(XDP, dt_w, dt_b, DTF, T_TOK, DI);
        gemm_dt<<<dim3(DI / 64, T_TOK / 64), 256, 0, stream>>>(XDP + (size_t)T_TOK * XDP_LD, dt_w_b, dt_b_b, DTB, T_TOK, DI);
    }
    // 7-9. chunked scan (HLOC/SUMDT live in PART; xdbl partials dead)
    scan_chunk<false><<<dim3(DI / 256, BATCH, 2 * NCHUNK), 256, 0, stream>>>(
        DTF, DTB, XCF, XCB, XDP, A_log, A_log_b, D_skip, D_skip_b, HLOC, SUMDT, YCAT);
    scan_combine<<<(2 * BATCH * DI * NST) / 256, 256, 0, stream>>>(HLOC, SUMDT, A_log, A_log_b);
    scan_chunk<true><<<dim3(DI / 256, BATCH, 2 * NCHUNK), 256, 0, stream>>>(
        DTF, DTB, XCF, XCB, XDP, A_log, A_log_b, D_skip, D_skip_b, HLOC, SUMDT, YCAT);
    // 10. merge_wT = bf16(merge_w^T) (aliases XCF/XCB, safe after scan C)
    transpose_cvt<<<dim3(DI / 32, N2 / 32), dim3(32, 8), 0, stream>>>(merge_w, merge_wT, N2, DI);
    // 11. YM = silu(z) * (YCAT @ merge_w) (M=2048, N=2048, K=4096)
    if (s_merge) {
        mfma_gemm<3><<<dim3(DI / 128, T_TOK / 128, s_merge), 256, 0, stream>>>(
            YCAT, merge_wT, merge_wT, 1 << 30, nullptr, nullptr, nullptr, Pb, nullptr, nullptr,
            T_TOK, DI, N2);
        reduce_gate<<<(int)(MNm / 4 / 256), 256, 0, stream>>>(Pb, s_merge, MNm, XZ, YM);
    } else {
        mfma_gemm<0><<<dim3(DI / 128, T_TOK / 128), 256, 0, stream>>>(
            YCAT, merge_wT, merge_wT, 1 << 30, YM, nullptr, nullptr, nullptr, nullptr, nullptr,
            T_TOK, DI, N2);
        gate_kernel<<<(T_TOK * DI) / 256, 256, 0, stream>>>(YM, XZ);
    }
    // 12. out = x + YM @ out_w (M=2048, N=1024, K=2048), f32
    if (s_out) {
        mfma_gemm<3><<<dim3(DM / 128, T_TOK / 128, s_out), 256, 0, stream>>>(
            YM, out_wT, out_wT, 1 << 30, nullptr, nullptr, nullptr, Pb, nullptr, nullptr,
            T_TOK, DM, DI);
        reduce_out<<<(int)(MNo / 4 / 256), 256, 0, stream>>>(Pb, s_out, MNo, x, out);
    } else {
        mfma_gemm<1><<<dim3(DM / 128, T_TOK / 128), 256, 0, stream>>>(
            YM, out_wT, out_wT, 1 << 30, nullptr, x, out, nullptr, nullptr, nullptr,
            T_TOK, DM, DI);
    }
}